// Round 3
// baseline (3710.270 us; speedup 1.0000x reference)
//
#include <hip/hip_runtime.h>

typedef unsigned short ushort_t;
typedef unsigned int u32;
typedef float f32x4 __attribute__((ext_vector_type(4)));
typedef __bf16 bf16x8 __attribute__((ext_vector_type(8)));

#define B_ 8
#define L_ 4096
#define D_ 384
#define DI_ 768
#define S_ 16
#define NC_ 40
#define ML_ (B_*L_)   // 32768 rows
#define NCHUNK 32
#define CL 128        // chunk length (L_/NCHUNK)

// ---------------- workspace layout (bytes) ----------------
// ~154 MB total. Aliasing:
//   XN lives in XC region (dead after gemm1, before conv writes XC);
//   XDBL lives at start of XP region (XP dead after conv);
//   FX (chunk summaries, 38.5 MB) lives in XP region after XDBL.
constexpr size_t au(size_t x){ return (x + 255) & ~size_t(255); }
constexpr size_t O_FLAG = 0;                                   // int
constexpr size_t O_LNW  = 256;                                 // 384 f32
constexpr size_t O_CONVW= au(O_LNW  + 384*4);                  // 3072 f32
constexpr size_t O_CONVB= au(O_CONVW+ 3072*4);                 // 768 f32
constexpr size_t O_WDT  = au(O_CONVB+ 768*4);                  // 18432 f32
constexpr size_t O_DTB  = au(O_WDT  + 18432*4);                // 768 f32
constexpr size_t O_A    = au(O_DTB  + 768*4);                  // 12288 f32 (A = -exp(A_log)*log2e)
constexpr size_t O_DSKIP= au(O_A    + 12288*4);                // 768 f32
constexpr size_t O_WOUT = au(O_DSKIP+ 768*4);                  // 294912 f32
constexpr size_t O_WFC  = au(O_WOUT + 294912*4);               // 98304 f32
constexpr size_t O_BFC  = au(O_WFC  + 98304*4);                // 256 f32
constexpr size_t O_GAM  = au(O_BFC  + 256*4);
constexpr size_t O_BET  = au(O_GAM  + 256*4);
constexpr size_t O_WCLS = au(O_BET  + 256*4);                  // 10240 f32
constexpr size_t O_BCLS = au(O_WCLS + 10240*4);                // 40 f32
constexpr size_t O_XMEAN= au(O_BCLS + 40*4);                   // 8*384 f32 (atomic acc, zeroed in prep)
constexpr size_t O_YMEAN= au(O_XMEAN+ 3072*4);                 // 8*768 f32
constexpr size_t O_H    = au(O_YMEAN+ 6144*4);                 // 8*256 f32
constexpr size_t O_WINT = au(O_H    + 2048*4);                 // W_in^T  [1536][384] bf16
constexpr size_t O_WXT  = au(O_WINT + (size_t)589824*2);       // W_xproj^T padded [64][768] bf16
constexpr size_t O_XP   = au(O_WXT  + (size_t)49152*2);        // [32768][768] bf16
constexpr size_t O_XDBL = O_XP;                                // alias: [32768][56] f32 (after conv)
constexpr size_t O_FX   = au(O_XDBL + (size_t)ML_*56*4);       // [b][c][49][768] f32 chunk summaries
constexpr size_t FX_SZ  = (size_t)B_*NCHUNK*49*768*4;          // 38.5 MB
constexpr size_t O_Z    = au(O_XP   + (size_t)ML_*768*2);      // [32768][768] bf16 (holds silu(z))
constexpr size_t O_XCU  = au(O_Z    + (size_t)ML_*768*2);      // union region, 50.3 MB
constexpr size_t O_XN   = O_XCU;                               // [32768][384] bf16 (dead after gemm1)
constexpr size_t O_XC   = O_XCU;                               // [32768][768] bf16
constexpr size_t WS_NEED= O_XCU + (size_t)ML_*768*2;           // ~154 MB
static_assert(O_FX + FX_SZ <= O_Z, "FX must fit in dead XP tail");

// ---------------- helpers ----------------
__device__ inline float bf2f(ushort_t u){ return __uint_as_float(((u32)u) << 16); }
__device__ inline ushort_t f2bf(float f){
    u32 x = __float_as_uint(f);
    u32 r = (x + 0x7fffu + ((x >> 16) & 1u)) >> 16;   // RNE
    return (ushort_t)r;
}
__device__ inline float ldf(const void* p, long i, int flag){
    return flag ? bf2f(((const ushort_t*)p)[i]) : ((const float*)p)[i];
}
__device__ inline ushort_t ldbf(const void* p, long i, int flag){
    return flag ? ((const ushort_t*)p)[i] : f2bf(((const float*)p)[i]);
}
__device__ inline float sigm(float v){ return 1.f / (1.f + __expf(-v)); }

__device__ inline void gload_lds16(const void* g, void* l){
    __builtin_amdgcn_global_load_lds(
        (const __attribute__((address_space(1))) u32*)g,
        (__attribute__((address_space(3))) u32*)l, 16, 0, 0);
}

struct Ptrs { const void* p[17]; };

// ---------------- k0: dtype detect ----------------
__global__ void k_detect(const void* x, char* ws){
    __shared__ float s[256];
    int tid = threadIdx.x;
    s[tid] = fabsf(bf2f(((const ushort_t*)x)[tid]));
    __syncthreads();
    for (int st = 128; st > 0; st >>= 1){
        if (tid < st) s[tid] = fmaxf(s[tid], s[tid + st]);
        __syncthreads();
    }
    if (tid == 0) *(int*)(ws + O_FLAG) = (s[0] < 1e4f) ? 1 : 0;
}

// ---------------- k1: weight prep ----------------
#define N_PREP 1082792L
__global__ __launch_bounds__(256) void k_prep(Ptrs ps, char* ws){
    const int flag = *(const int*)(ws + O_FLAG);
    long o = (long)blockIdx.x * 256 + threadIdx.x;
    if (o < 384){ ((float*)(ws+O_LNW))[o]  = ldf(ps.p[1],o,flag); return; }  o -= 384;
    if (o < 3072){ ((float*)(ws+O_CONVW))[o]= ldf(ps.p[3],o,flag); return; } o -= 3072;
    if (o < 768){ ((float*)(ws+O_CONVB))[o]= ldf(ps.p[4],o,flag); return; }  o -= 768;
    if (o < 18432){ ((float*)(ws+O_WDT))[o]= ldf(ps.p[6],o,flag); return; }  o -= 18432;
    if (o < 768){ ((float*)(ws+O_DTB))[o]  = ldf(ps.p[7],o,flag); return; }  o -= 768;
    if (o < 768){ ((float*)(ws+O_DSKIP))[o]= ldf(ps.p[9],o,flag); return; }  o -= 768;
    if (o < 294912){ ((float*)(ws+O_WOUT))[o]= ldf(ps.p[10],o,flag); return; } o -= 294912;
    if (o < 98304){ ((float*)(ws+O_WFC))[o]= ldf(ps.p[11],o,flag); return; } o -= 98304;
    if (o < 256){ ((float*)(ws+O_BFC))[o]  = ldf(ps.p[12],o,flag); return; } o -= 256;
    if (o < 256){ ((float*)(ws+O_GAM))[o]  = ldf(ps.p[13],o,flag); return; } o -= 256;
    if (o < 256){ ((float*)(ws+O_BET))[o]  = ldf(ps.p[14],o,flag); return; } o -= 256;
    if (o < 10240){ ((float*)(ws+O_WCLS))[o]= ldf(ps.p[15],o,flag); return; } o -= 10240;
    if (o < 40){ ((float*)(ws+O_BCLS))[o]  = ldf(ps.p[16],o,flag); return; } o -= 40;
    // A = -exp(A_log) * log2(e)   (scan uses exp2)
    if (o < 12288){ ((float*)(ws+O_A))[o]  = -__expf(ldf(ps.p[8],o,flag)) * 1.4426950408889634f; return; } o -= 12288;
    if (o < 589824){                     // W_in [384,1536] -> WinT [1536][384]
        long n = o / 384, k = o % 384;
        ((ushort_t*)(ws+O_WINT))[o] = ldbf(ps.p[2], k*1536 + n, flag); return;
    } o -= 589824;
    if (o < 49152){                      // W_xproj [768,56] -> WxT [64][768], zero-pad n>=56
        long n = o / 768, k = o % 768;
        ((ushort_t*)(ws+O_WXT))[o] = (n < 56) ? ldbf(ps.p[5], k*56 + n, flag) : (ushort_t)0;
        return;
    } o -= 49152;
    if (o < 3072){ ((float*)(ws+O_XMEAN))[o] = 0.f; return; }
}

// ---------------- k2: RMSNorm -> xn (bf16) ----------------
__global__ __launch_bounds__(128) void k_rmsnorm(const void* x, char* ws){
    const int flag = *(const int*)(ws + O_FLAG);
    const float* lnw = (const float*)(ws + O_LNW);
    ushort_t* xn = (ushort_t*)(ws + O_XN);
    long row = blockIdx.x;
    int tid = threadIdx.x;
    float v[3];
    if (flag){
        const ushort_t* xb = (const ushort_t*)x;
        #pragma unroll
        for (int c = 0; c < 3; c++) v[c] = bf2f(xb[row*384 + tid + c*128]);
    } else {
        const float* xf = (const float*)x;
        #pragma unroll
        for (int c = 0; c < 3; c++) v[c] = xf[row*384 + tid + c*128];
    }
    __shared__ float red[128];
    red[tid] = v[0]*v[0] + v[1]*v[1] + v[2]*v[2];
    __syncthreads();
    for (int st = 64; st > 0; st >>= 1){
        if (tid < st) red[tid] += red[tid + st];
        __syncthreads();
    }
    float scale = rsqrtf(red[0] * (1.f/384.f) + 1e-5f);
    #pragma unroll
    for (int c = 0; c < 3; c++)
        xn[row*384 + tid + c*128] = f2bf(v[c] * scale * lnw[tid + c*128]);
}

// ---------------- k3: xmean[b,d] = mean_L x ----------------
__global__ __launch_bounds__(256) void k_xmean(const void* x, char* ws){
    const int flag = *(const int*)(ws + O_FLAG);
    float* xmean = (float*)(ws + O_XMEAN);
    int b = blockIdx.x, d0 = blockIdx.y*128, l0 = blockIdx.z*256;
    int tid = threadIdx.x, dl = tid & 127, lh = tid >> 7;
    float acc = 0.f;
    if (flag){
        const ushort_t* xb = (const ushort_t*)x;
        for (int l = l0 + lh; l < l0 + 256; l += 2)
            acc += bf2f(xb[((long)b*L_ + l)*384 + d0 + dl]);
    } else {
        const float* xf = (const float*)x;
        for (int l = l0 + lh; l < l0 + 256; l += 2)
            acc += xf[((long)b*L_ + l)*384 + d0 + dl];
    }
    __shared__ float s[256];
    s[tid] = acc; __syncthreads();
    if (tid < 128)
        atomicAdd(&xmean[b*384 + d0 + dl], (s[tid] + s[tid+128]) * (1.f/L_));
}

// ---------------- k4: GEMM1  xn @ W_in -> xp | silu(z) ---------
__global__ __launch_bounds__(256) void k_gemm1(char* ws){
    const ushort_t* xn = (const ushort_t*)(ws + O_XN);
    const ushort_t* wT = (const ushort_t*)(ws + O_WINT);
    ushort_t* xp = (ushort_t*)(ws + O_XP);
    ushort_t* zz = (ushort_t*)(ws + O_Z);
    __shared__ ushort_t sA[128*32];
    __shared__ ushort_t sB[128*32];
    int tid = threadIdx.x, w = tid >> 6, l = tid & 63;
    long m0 = (long)blockIdx.x * 128;
    int n0 = blockIdx.y * 128;
    f32x4 acc[4][4] = {};
    int lr = l >> 2, lk = (l & 3) * 8;
    const ushort_t* gA = xn + (m0 + w*16 + lr)*384 + lk;
    const ushort_t* gB = wT + ((long)(n0 + w*16 + lr))*384 + lk;
    ushort_t* lA = &sA[w*16*32];
    ushort_t* lB = &sB[w*16*32];
    int wm = w & 1, wn = w >> 1;
    int arow = wm*64 + (l & 15);
    int brow = wn*64 + (l & 15);
    int koff = (l >> 4) * 8;
    for (int kc = 0; kc < 12; kc++){
        int k0 = kc * 32;
        gload_lds16(gA + k0,           lA);
        gload_lds16(gA + k0 + 64*384,  lA + 64*32);
        gload_lds16(gB + k0,           lB);
        gload_lds16(gB + k0 + 64*384,  lB + 64*32);
        __syncthreads();
        bf16x8 af[4], bfv[4];
        #pragma unroll
        for (int i = 0; i < 4; i++){
            af[i]  = *(const bf16x8*)&sA[(arow + i*16)*32 + koff];
            bfv[i] = *(const bf16x8*)&sB[(brow + i*16)*32 + koff];
        }
        #pragma unroll
        for (int mb = 0; mb < 4; mb++)
            #pragma unroll
            for (int nb = 0; nb < 4; nb++)
                acc[mb][nb] = __builtin_amdgcn_mfma_f32_16x16x32_bf16(af[mb], bfv[nb], acc[mb][nb], 0, 0, 0);
        __syncthreads();
    }
    ushort_t* outp; int nc0; bool isz;
    if (n0 < 768){ outp = xp; nc0 = n0; isz = false; }
    else { outp = zz; nc0 = n0 - 768; isz = true; }
    int rbase = (l >> 4) * 4, cl = l & 15;
    #pragma unroll
    for (int mb = 0; mb < 4; mb++)
        #pragma unroll
        for (int nb = 0; nb < 4; nb++){
            long row = m0 + wm*64 + mb*16 + rbase;
            int col = nc0 + wn*64 + nb*16 + cl;
            #pragma unroll
            for (int r = 0; r < 4; r++){
                float v = acc[mb][nb][r];
                if (isz) v = v * sigm(v);        // fused silu for z
                outp[(row + r)*768 + col] = f2bf(v);
            }
        }
}

// ---------------- k5: causal depthwise conv K=4 + SiLU ----------------
__global__ __launch_bounds__(256) void k_conv(char* ws){
    const ushort_t* xp = (const ushort_t*)(ws + O_XP);
    ushort_t* xc = (ushort_t*)(ws + O_XC);
    const float* cw = (const float*)(ws + O_CONVW);
    const float* cb = (const float*)(ws + O_CONVB);
    int d = blockIdx.x*256 + threadIdx.x;
    int t0 = blockIdx.y * 8;
    int b = blockIdx.z;
    long rbase = (long)b * L_;
    float w0 = cw[d*4], w1 = cw[d*4+1], w2 = cw[d*4+2], w3 = cw[d*4+3];
    float bias = cb[d];
    float xv[11];
    #pragma unroll
    for (int i = 0; i < 11; i++){
        int t = t0 - 3 + i;
        xv[i] = (t >= 0) ? bf2f(xp[(rbase + t)*768 + d]) : 0.f;
    }
    #pragma unroll
    for (int tt = 0; tt < 8; tt++){
        float v = bias + xv[tt]*w0 + xv[tt+1]*w1 + xv[tt+2]*w2 + xv[tt+3]*w3;
        v = v * sigm(v);
        xc[(rbase + t0 + tt)*768 + d] = f2bf(v);
    }
}

// ---------------- k6: xproj  xc @ W_xproj -> x_dbl[32768,56] ----
__global__ __launch_bounds__(256) void k_xproj(char* ws){
    const ushort_t* xc = (const ushort_t*)(ws + O_XC);
    const ushort_t* wT = (const ushort_t*)(ws + O_WXT);
    float* xdbl = (float*)(ws + O_XDBL);
    __shared__ ushort_t sA[128*32];
    __shared__ ushort_t sB[64*32];
    int tid = threadIdx.x, w = tid >> 6, l = tid & 63;
    long m0 = (long)blockIdx.x * 128;
    f32x4 acc[2][4] = {};
    int lr = l >> 2, lk = (l & 3) * 8;
    const ushort_t* gA = xc + (m0 + w*16 + lr)*768 + lk;
    const ushort_t* gB = wT + ((long)(w*16 + lr))*768 + lk;
    ushort_t* lA = &sA[w*16*32];
    ushort_t* lB = &sB[w*16*32];
    int arow0 = w*32 + (l & 15);
    int brow = l & 15;
    int koff = (l >> 4) * 8;
    for (int kc = 0; kc < 24; kc++){
        int k0 = kc * 32;
        gload_lds16(gA + k0,           lA);
        gload_lds16(gA + k0 + 64*768,  lA + 64*32);
        gload_lds16(gB + k0,           lB);
        __syncthreads();
        bf16x8 af[2], bfv[4];
        af[0] = *(const bf16x8*)&sA[arow0*32 + koff];
        af[1] = *(const bf16x8*)&sA[(arow0+16)*32 + koff];
        #pragma unroll
        for (int nb = 0; nb < 4; nb++)
            bfv[nb] = *(const bf16x8*)&sB[(nb*16 + brow)*32 + koff];
        #pragma unroll
        for (int mb = 0; mb < 2; mb++)
            #pragma unroll
            for (int nb = 0; nb < 4; nb++)
                acc[mb][nb] = __builtin_amdgcn_mfma_f32_16x16x32_bf16(af[mb], bfv[nb], acc[mb][nb], 0, 0, 0);
        __syncthreads();
    }
    int rbase = (l >> 4) * 4, cl = l & 15;
    #pragma unroll
    for (int mb = 0; mb < 2; mb++)
        #pragma unroll
        for (int nb = 0; nb < 4; nb++){
            int col = nb*16 + cl;
            if (col < 56){
                long row = m0 + w*32 + mb*16 + rbase;
                #pragma unroll
                for (int r = 0; r < 4; r++)
                    xdbl[(row + r)*56 + col] = acc[mb][nb][r];
            }
        }
}

// ---------------- k7: chunk-parallel selective scan (pass 1) --------------
// Linear recurrence h_t = dA_t*h_t-1 + u_t*B_t is associative: each block
// handles one (b, chunk, dgroup-of-256); thread = one d, h/q/G[16] in VGPRs.
// Emits per (b,c,d): ysum0, H[16] (end state from 0-init), P[16] (decay
// product), G[16] (correction functional). Pass 2 stitches chunks.
__global__ __launch_bounds__(256, 3) void k_scan(char* ws){
    const ushort_t* xc = (const ushort_t*)(ws + O_XC);
    const ushort_t* wz = (const ushort_t*)(ws + O_Z);      // silu(z)
    const float* xdbl = (const float*)(ws + O_XDBL);
    const float* Ag = (const float*)(ws + O_A);            // -exp(A_log)*log2e
    const float* Dsk = (const float*)(ws + O_DSKIP);
    const float* Wdt = (const float*)(ws + O_WDT);
    const float* dtb = (const float*)(ws + O_DTB);
    float* FX = (float*)(ws + O_FX);
    int tid = threadIdx.x;
    int d = blockIdx.x * 256 + tid;
    int c = blockIdx.y;
    int b = blockIdx.z;
    long row0 = (long)b * L_ + (long)c * CL;

    float wdt[24];
    #pragma unroll
    for (int k = 0; k < 24; k++) wdt[k] = Wdt[k*768 + d];
    float dbias = dtb[d];
    float Av[16];
    #pragma unroll
    for (int s = 0; s < 16; s++) Av[s] = Ag[d*16 + s];
    float Dv = Dsk[d];

    __shared__ float sXD[CL*56];                 // chunk's xdbl rows
    #pragma unroll
    for (int i = 0; i < 28; i++)
        sXD[tid + i*256] = xdbl[row0*56 + tid + i*256];
    __syncthreads();

    float h[16], q[16], G[16];
    #pragma unroll
    for (int s = 0; s < 16; s++){ h[s] = 0.f; q[s] = 1.f; G[s] = 0.f; }
    float ysum = 0.f;

    #pragma unroll 2
    for (int tg = 0; tg < CL/8; tg++){
        ushort_t xcu[8], zu[8];
        #pragma unroll
        for (int i = 0; i < 8; i++){
            long r = (row0 + tg*8 + i)*768 + d;
            xcu[i] = xc[r];
            zu[i]  = wz[r];
        }
        #pragma unroll
        for (int i = 0; i < 8; i++){
            int t = tg*8 + i;
            const f32x4* xd4 = (const f32x4*)&sXD[t*56];
            // dt = softplus(dt_r @ wdt + bias)
            float dtv = dbias;
            #pragma unroll
            for (int j = 0; j < 6; j++){
                f32x4 v = xd4[j];
                dtv += v[0]*wdt[j*4] + v[1]*wdt[j*4+1] + v[2]*wdt[j*4+2] + v[3]*wdt[j*4+3];
            }
            dtv = (dtv > 20.f) ? dtv : 0.69314718056f * __log2f(1.f + exp2f(dtv * 1.4426950409f));
            float xcv = bf2f(xcu[i]);
            float wzv = bf2f(zu[i]);
            float u = dtv * xcv;
            float yp = 0.f;
            f32x4 Bv0 = xd4[6], Bv1 = xd4[7], Bv2 = xd4[8], Bv3 = xd4[9];
            f32x4 Cv0 = xd4[10], Cv1 = xd4[11], Cv2 = xd4[12], Cv3 = xd4[13];
            #pragma unroll
            for (int s = 0; s < 16; s++){
                float Bs = (s<4? Bv0[s&3] : s<8? Bv1[s&3] : s<12? Bv2[s&3] : Bv3[s&3]);
                float Cs = (s<4? Cv0[s&3] : s<8? Cv1[s&3] : s<12? Cv2[s&3] : Cv3[s&3]);
                float dA = exp2f(dtv * Av[s]);
                h[s] = dA*h[s] + u*Bs;
                float Cw = Cs * wzv;
                yp += h[s] * Cw;
                q[s] *= dA;
                G[s] += q[s] * Cw;
            }
            ysum += yp + xcv * Dv * wzv;
        }
    }
    long fb = ((long)(b*NCHUNK + c)*49)*768 + d;
    FX[fb] = ysum;
    #pragma unroll
    for (int s = 0; s < 16; s++){
        FX[fb + (1+s)*768]  = h[s];
        FX[fb + (17+s)*768] = q[s];
        FX[fb + (33+s)*768] = G[s];
    }
}

// ---------------- k8: scan pass 2 — stitch chunks, emit ymean -------------
__global__ __launch_bounds__(256) void k_fix(char* ws){
    const float* FX = (const float*)(ws + O_FX);
    float* ymean = (float*)(ws + O_YMEAN);
    int d = blockIdx.x * 256 + threadIdx.x;
    int b = blockIdx.y;
    float Hrun[16];
    #pragma unroll
    for (int s = 0; s < 16; s++) Hrun[s] = 0.f;
    float ys = 0.f;
    for (int c = 0; c < NCHUNK; c++){
        long fb = ((long)(b*NCHUNK + c)*49)*768 + d;
        ys += FX[fb];
        #pragma unroll
        for (int s = 0; s < 16; s++) ys += Hrun[s] * FX[fb + (33+s)*768];
        #pragma unroll
        for (int s = 0; s < 16; s++) Hrun[s] = FX[fb + (1+s)*768] + FX[fb + (17+s)*768] * Hrun[s];
    }
    ymean[b*768 + d] = ys * (1.f/L_);
}

// ---------------- k9: head part 1: pooled -> h = pooled@W_fc + b_fc ------
__global__ __launch_bounds__(256) void k_head1(char* ws){
    const float* ymean = (const float*)(ws + O_YMEAN);
    const float* xmean = (const float*)(ws + O_XMEAN);
    const float* Wout = (const float*)(ws + O_WOUT);
    const float* Wfc = (const float*)(ws + O_WFC);
    const float* bfc = (const float*)(ws + O_BFC);
    float* hbuf = (float*)(ws + O_H);
    int b = blockIdx.x, tid = threadIdx.x;
    __shared__ float sY[768];
    __shared__ float sP[384];
    sY[tid] = ymean[b*768 + tid];
    sY[tid+256] = ymean[b*768 + tid + 256];
    sY[tid+512] = ymean[b*768 + tid + 512];
    __syncthreads();
    for (int d = tid; d < 384; d += 256){
        float v = xmean[b*384 + d];
        for (int i = 0; i < 768; i++) v += sY[i] * Wout[i*384 + d];
        sP[d] = v;
    }
    __syncthreads();
    float v = bfc[tid];
    for (int dd = 0; dd < 384; dd++) v += sP[dd] * Wfc[dd*256 + tid];
    hbuf[b*256 + tid] = v;
}

// ---------------- k10: head part 2: batchnorm + relu + classifier --------
__global__ __launch_bounds__(384) void k_head2(char* ws, void* out){
    const int flag = *(const int*)(ws + O_FLAG);
    const float* hbuf = (const float*)(ws + O_H);
    const float* gam = (const float*)(ws + O_GAM);
    const float* bet = (const float*)(ws + O_BET);
    const float* Wcls = (const float*)(ws + O_WCLS);
    const float* bcls = (const float*)(ws + O_BCLS);
    int tid = threadIdx.x;
    __shared__ float sH[8*256];
    if (tid < 256){
        float hv[8]; float mu = 0.f;
        #pragma unroll
        for (int b = 0; b < 8; b++){ hv[b] = hbuf[b*256 + tid]; mu += hv[b]; }
        mu *= 0.125f;
        float var = 0.f;
        #pragma unroll
        for (int b = 0; b < 8; b++){ float dv = hv[b]-mu; var += dv*dv; }
        var *= 0.125f;
        float rs = rsqrtf(var + 1e-5f);
        #pragma unroll
        for (int b = 0; b < 8; b++){
            float t = (hv[b]-mu)*rs*gam[tid] + bet[tid];
            sH[b*256 + tid] = t > 0.f ? t : 0.f;
        }
    }
    __syncthreads();
    if (tid < 320){
        int b = tid / 40, c = tid % 40;
        float acc = bcls[c];
        for (int j = 0; j < 256; j++) acc += sH[b*256 + j] * Wcls[j*40 + c];
        if (flag) ((ushort_t*)out)[b*40 + c] = f2bf(acc);
        else      ((float*)out)[b*40 + c] = acc;
    }
}

// ---------------- launch ----------------
extern "C" void kernel_launch(void* const* d_in, const int* in_sizes, int n_in,
                              void* d_out, int out_size, void* d_ws, size_t ws_size,
                              hipStream_t stream){
    (void)in_sizes; (void)n_in; (void)out_size; (void)ws_size;
    char* ws = (char*)d_ws;
    Ptrs ps;
    for (int i = 0; i < 17; i++) ps.p[i] = d_in[i];

    k_detect<<<1, 256, 0, stream>>>(d_in[0], ws);
    k_prep<<<(unsigned)((N_PREP + 255) / 256), 256, 0, stream>>>(ps, ws);
    k_rmsnorm<<<ML_, 128, 0, stream>>>(d_in[0], ws);
    k_xmean<<<dim3(8, 3, 16), 256, 0, stream>>>(d_in[0], ws);
    k_gemm1<<<dim3(ML_/128, 12), 256, 0, stream>>>(ws);
    k_conv<<<dim3(3, L_/8, B_), 256, 0, stream>>>(ws);
    k_xproj<<<ML_/128, 256, 0, stream>>>(ws);
    k_scan<<<dim3(3, NCHUNK, B_), 256, 0, stream>>>(ws);
    k_fix<<<dim3(3, B_), 256, 0, stream>>>(ws);
    k_head1<<<B_, 256, 0, stream>>>(ws);
    k_head2<<<1, 384, 0, stream>>>(ws, d_out);
}

// Round 4
// 571.158 us; speedup vs baseline: 6.4960x; 6.4960x over previous
//
#include <hip/hip_runtime.h>

typedef unsigned short ushort_t;
typedef unsigned int u32;
typedef float f32x4 __attribute__((ext_vector_type(4)));
typedef __bf16 bf16x8 __attribute__((ext_vector_type(8)));

#define B_ 8
#define L_ 4096
#define D_ 384
#define DI_ 768
#define S_ 16
#define NC_ 40
#define ML_ (B_*L_)   // 32768 rows
#define NCHUNK 32
#define CL 128        // chunk length (L_/NCHUNK)

// ---------------- workspace layout (bytes) ----------------
// ~154 MB total. Aliasing:
//   XN lives in XC region (dead after gemm1, before conv writes XC);
//   XDBL lives at start of XP region (XP dead after conv);
//   FX (chunk summaries, 38.5 MB) lives in XP region after XDBL.
constexpr size_t au(size_t x){ return (x + 255) & ~size_t(255); }
constexpr size_t O_FLAG = 0;                                   // int
constexpr size_t O_LNW  = 256;                                 // 384 f32
constexpr size_t O_CONVW= au(O_LNW  + 384*4);                  // 3072 f32
constexpr size_t O_CONVB= au(O_CONVW+ 3072*4);                 // 768 f32
constexpr size_t O_WDT  = au(O_CONVB+ 768*4);                  // 18432 f32
constexpr size_t O_DTB  = au(O_WDT  + 18432*4);                // 768 f32
constexpr size_t O_A    = au(O_DTB  + 768*4);                  // 12288 f32 (A = -exp(A_log)*log2e)
constexpr size_t O_DSKIP= au(O_A    + 12288*4);                // 768 f32
constexpr size_t O_WOUT = au(O_DSKIP+ 768*4);                  // 294912 f32
constexpr size_t O_WFC  = au(O_WOUT + 294912*4);               // 98304 f32
constexpr size_t O_BFC  = au(O_WFC  + 98304*4);                // 256 f32
constexpr size_t O_GAM  = au(O_BFC  + 256*4);
constexpr size_t O_BET  = au(O_GAM  + 256*4);
constexpr size_t O_WCLS = au(O_BET  + 256*4);                  // 10240 f32
constexpr size_t O_BCLS = au(O_WCLS + 10240*4);                // 40 f32
constexpr size_t O_XMEAN= au(O_BCLS + 40*4);                   // 8*384 f32 (atomic acc, zeroed in prep)
constexpr size_t O_YMEAN= au(O_XMEAN+ 3072*4);                 // 8*768 f32
constexpr size_t O_H    = au(O_YMEAN+ 6144*4);                 // 8*256 f32
constexpr size_t O_WINT = au(O_H    + 2048*4);                 // W_in^T  [1536][384] bf16
constexpr size_t O_WXT  = au(O_WINT + (size_t)589824*2);       // W_xproj^T padded [64][768] bf16
constexpr size_t O_XP   = au(O_WXT  + (size_t)49152*2);        // [32768][768] bf16
constexpr size_t O_XDBL = O_XP;                                // alias: [32768][56] f32 (after conv)
constexpr size_t O_FX   = au(O_XDBL + (size_t)ML_*56*4);       // [b][c][49][768] f32 chunk summaries
constexpr size_t FX_SZ  = (size_t)B_*NCHUNK*49*768*4;          // 38.5 MB
constexpr size_t O_Z    = au(O_XP   + (size_t)ML_*768*2);      // [32768][768] bf16 (holds silu(z))
constexpr size_t O_XCU  = au(O_Z    + (size_t)ML_*768*2);      // union region, 50.3 MB
constexpr size_t O_XN   = O_XCU;                               // [32768][384] bf16 (dead after gemm1)
constexpr size_t O_XC   = O_XCU;                               // [32768][768] bf16
constexpr size_t WS_NEED= O_XCU + (size_t)ML_*768*2;           // ~154 MB
static_assert(O_FX + FX_SZ <= O_Z, "FX must fit in dead XP tail");

// ---------------- helpers ----------------
__device__ inline float bf2f(ushort_t u){ return __uint_as_float(((u32)u) << 16); }
__device__ inline ushort_t f2bf(float f){
    u32 x = __float_as_uint(f);
    u32 r = (x + 0x7fffu + ((x >> 16) & 1u)) >> 16;   // RNE
    return (ushort_t)r;
}
__device__ inline float ldf(const void* p, long i, int flag){
    return flag ? bf2f(((const ushort_t*)p)[i]) : ((const float*)p)[i];
}
__device__ inline ushort_t ldbf(const void* p, long i, int flag){
    return flag ? ((const ushort_t*)p)[i] : f2bf(((const float*)p)[i]);
}
__device__ inline float sigm(float v){ return 1.f / (1.f + __expf(-v)); }

__device__ inline void gload_lds16(const void* g, void* l){
    __builtin_amdgcn_global_load_lds(
        (const __attribute__((address_space(1))) u32*)g,
        (__attribute__((address_space(3))) u32*)l, 16, 0, 0);
}

struct Ptrs { const void* p[17]; };

// ---------------- k0: dtype detect ----------------
__global__ void k_detect(const void* x, char* ws){
    __shared__ float s[256];
    int tid = threadIdx.x;
    s[tid] = fabsf(bf2f(((const ushort_t*)x)[tid]));
    __syncthreads();
    for (int st = 128; st > 0; st >>= 1){
        if (tid < st) s[tid] = fmaxf(s[tid], s[tid + st]);
        __syncthreads();
    }
    if (tid == 0) *(int*)(ws + O_FLAG) = (s[0] < 1e4f) ? 1 : 0;
}

// ---------------- k1: weight prep ----------------
#define N_PREP 1082792L
__global__ __launch_bounds__(256) void k_prep(Ptrs ps, char* ws){
    const int flag = *(const int*)(ws + O_FLAG);
    long o = (long)blockIdx.x * 256 + threadIdx.x;
    if (o < 384){ ((float*)(ws+O_LNW))[o]  = ldf(ps.p[1],o,flag); return; }  o -= 384;
    if (o < 3072){ ((float*)(ws+O_CONVW))[o]= ldf(ps.p[3],o,flag); return; } o -= 3072;
    if (o < 768){ ((float*)(ws+O_CONVB))[o]= ldf(ps.p[4],o,flag); return; }  o -= 768;
    if (o < 18432){ ((float*)(ws+O_WDT))[o]= ldf(ps.p[6],o,flag); return; }  o -= 18432;
    if (o < 768){ ((float*)(ws+O_DTB))[o]  = ldf(ps.p[7],o,flag); return; }  o -= 768;
    if (o < 768){ ((float*)(ws+O_DSKIP))[o]= ldf(ps.p[9],o,flag); return; }  o -= 768;
    if (o < 294912){ ((float*)(ws+O_WOUT))[o]= ldf(ps.p[10],o,flag); return; } o -= 294912;
    if (o < 98304){ ((float*)(ws+O_WFC))[o]= ldf(ps.p[11],o,flag); return; } o -= 98304;
    if (o < 256){ ((float*)(ws+O_BFC))[o]  = ldf(ps.p[12],o,flag); return; } o -= 256;
    if (o < 256){ ((float*)(ws+O_GAM))[o]  = ldf(ps.p[13],o,flag); return; } o -= 256;
    if (o < 256){ ((float*)(ws+O_BET))[o]  = ldf(ps.p[14],o,flag); return; } o -= 256;
    if (o < 10240){ ((float*)(ws+O_WCLS))[o]= ldf(ps.p[15],o,flag); return; } o -= 10240;
    if (o < 40){ ((float*)(ws+O_BCLS))[o]  = ldf(ps.p[16],o,flag); return; } o -= 40;
    // A = -exp(A_log) * log2(e)   (scan uses exp2)
    if (o < 12288){ ((float*)(ws+O_A))[o]  = -__expf(ldf(ps.p[8],o,flag)) * 1.4426950408889634f; return; } o -= 12288;
    if (o < 589824){                     // W_in [384,1536] -> WinT [1536][384]
        long n = o / 384, k = o % 384;
        ((ushort_t*)(ws+O_WINT))[o] = ldbf(ps.p[2], k*1536 + n, flag); return;
    } o -= 589824;
    if (o < 49152){                      // W_xproj [768,56] -> WxT [64][768], zero-pad n>=56
        long n = o / 768, k = o % 768;
        ((ushort_t*)(ws+O_WXT))[o] = (n < 56) ? ldbf(ps.p[5], k*56 + n, flag) : (ushort_t)0;
        return;
    } o -= 49152;
    if (o < 3072){ ((float*)(ws+O_XMEAN))[o] = 0.f; return; }
}

// ---------------- k2: RMSNorm -> xn (bf16) ----------------
__global__ __launch_bounds__(128) void k_rmsnorm(const void* x, char* ws){
    const int flag = *(const int*)(ws + O_FLAG);
    const float* lnw = (const float*)(ws + O_LNW);
    ushort_t* xn = (ushort_t*)(ws + O_XN);
    long row = blockIdx.x;
    int tid = threadIdx.x;
    float v[3];
    if (flag){
        const ushort_t* xb = (const ushort_t*)x;
        #pragma unroll
        for (int c = 0; c < 3; c++) v[c] = bf2f(xb[row*384 + tid + c*128]);
    } else {
        const float* xf = (const float*)x;
        #pragma unroll
        for (int c = 0; c < 3; c++) v[c] = xf[row*384 + tid + c*128];
    }
    __shared__ float red[128];
    red[tid] = v[0]*v[0] + v[1]*v[1] + v[2]*v[2];
    __syncthreads();
    for (int st = 64; st > 0; st >>= 1){
        if (tid < st) red[tid] += red[tid + st];
        __syncthreads();
    }
    float scale = rsqrtf(red[0] * (1.f/384.f) + 1e-5f);
    #pragma unroll
    for (int c = 0; c < 3; c++)
        xn[row*384 + tid + c*128] = f2bf(v[c] * scale * lnw[tid + c*128]);
}

// ---------------- k3: xmean[b,d] = mean_L x ----------------
__global__ __launch_bounds__(256) void k_xmean(const void* x, char* ws){
    const int flag = *(const int*)(ws + O_FLAG);
    float* xmean = (float*)(ws + O_XMEAN);
    int b = blockIdx.x, d0 = blockIdx.y*128, l0 = blockIdx.z*256;
    int tid = threadIdx.x, dl = tid & 127, lh = tid >> 7;
    float acc = 0.f;
    if (flag){
        const ushort_t* xb = (const ushort_t*)x;
        for (int l = l0 + lh; l < l0 + 256; l += 2)
            acc += bf2f(xb[((long)b*L_ + l)*384 + d0 + dl]);
    } else {
        const float* xf = (const float*)x;
        for (int l = l0 + lh; l < l0 + 256; l += 2)
            acc += xf[((long)b*L_ + l)*384 + d0 + dl];
    }
    __shared__ float s[256];
    s[tid] = acc; __syncthreads();
    if (tid < 128)
        atomicAdd(&xmean[b*384 + d0 + dl], (s[tid] + s[tid+128]) * (1.f/L_));
}

// ---------------- k4: GEMM1  xn @ W_in -> xp | silu(z) ---------
__global__ __launch_bounds__(256) void k_gemm1(char* ws){
    const ushort_t* xn = (const ushort_t*)(ws + O_XN);
    const ushort_t* wT = (const ushort_t*)(ws + O_WINT);
    ushort_t* xp = (ushort_t*)(ws + O_XP);
    ushort_t* zz = (ushort_t*)(ws + O_Z);
    __shared__ ushort_t sA[128*32];
    __shared__ ushort_t sB[128*32];
    int tid = threadIdx.x, w = tid >> 6, l = tid & 63;
    long m0 = (long)blockIdx.x * 128;
    int n0 = blockIdx.y * 128;
    f32x4 acc[4][4] = {};
    int lr = l >> 2, lk = (l & 3) * 8;
    const ushort_t* gA = xn + (m0 + w*16 + lr)*384 + lk;
    const ushort_t* gB = wT + ((long)(n0 + w*16 + lr))*384 + lk;
    ushort_t* lA = &sA[w*16*32];
    ushort_t* lB = &sB[w*16*32];
    int wm = w & 1, wn = w >> 1;
    int arow = wm*64 + (l & 15);
    int brow = wn*64 + (l & 15);
    int koff = (l >> 4) * 8;
    for (int kc = 0; kc < 12; kc++){
        int k0 = kc * 32;
        gload_lds16(gA + k0,           lA);
        gload_lds16(gA + k0 + 64*384,  lA + 64*32);
        gload_lds16(gB + k0,           lB);
        gload_lds16(gB + k0 + 64*384,  lB + 64*32);
        __syncthreads();
        bf16x8 af[4], bfv[4];
        #pragma unroll
        for (int i = 0; i < 4; i++){
            af[i]  = *(const bf16x8*)&sA[(arow + i*16)*32 + koff];
            bfv[i] = *(const bf16x8*)&sB[(brow + i*16)*32 + koff];
        }
        #pragma unroll
        for (int mb = 0; mb < 4; mb++)
            #pragma unroll
            for (int nb = 0; nb < 4; nb++)
                acc[mb][nb] = __builtin_amdgcn_mfma_f32_16x16x32_bf16(af[mb], bfv[nb], acc[mb][nb], 0, 0, 0);
        __syncthreads();
    }
    ushort_t* outp; int nc0; bool isz;
    if (n0 < 768){ outp = xp; nc0 = n0; isz = false; }
    else { outp = zz; nc0 = n0 - 768; isz = true; }
    int rbase = (l >> 4) * 4, cl = l & 15;
    #pragma unroll
    for (int mb = 0; mb < 4; mb++)
        #pragma unroll
        for (int nb = 0; nb < 4; nb++){
            long row = m0 + wm*64 + mb*16 + rbase;
            int col = nc0 + wn*64 + nb*16 + cl;
            #pragma unroll
            for (int r = 0; r < 4; r++){
                float v = acc[mb][nb][r];
                if (isz) v = v * sigm(v);        // fused silu for z
                outp[(row + r)*768 + col] = f2bf(v);
            }
        }
}

// ---------------- k5: causal depthwise conv K=4 + SiLU ----------------
__global__ __launch_bounds__(256) void k_conv(char* ws){
    const ushort_t* xp = (const ushort_t*)(ws + O_XP);
    ushort_t* xc = (ushort_t*)(ws + O_XC);
    const float* cw = (const float*)(ws + O_CONVW);
    const float* cb = (const float*)(ws + O_CONVB);
    int d = blockIdx.x*256 + threadIdx.x;
    int t0 = blockIdx.y * 8;
    int b = blockIdx.z;
    long rbase = (long)b * L_;
    float w0 = cw[d*4], w1 = cw[d*4+1], w2 = cw[d*4+2], w3 = cw[d*4+3];
    float bias = cb[d];
    float xv[11];
    #pragma unroll
    for (int i = 0; i < 11; i++){
        int t = t0 - 3 + i;
        xv[i] = (t >= 0) ? bf2f(xp[(rbase + t)*768 + d]) : 0.f;
    }
    #pragma unroll
    for (int tt = 0; tt < 8; tt++){
        float v = bias + xv[tt]*w0 + xv[tt+1]*w1 + xv[tt+2]*w2 + xv[tt+3]*w3;
        v = v * sigm(v);
        xc[(rbase + t0 + tt)*768 + d] = f2bf(v);
    }
}

// ---------------- k6: xproj  xc @ W_xproj -> x_dbl[32768,56] ----
__global__ __launch_bounds__(256) void k_xproj(char* ws){
    const ushort_t* xc = (const ushort_t*)(ws + O_XC);
    const ushort_t* wT = (const ushort_t*)(ws + O_WXT);
    float* xdbl = (float*)(ws + O_XDBL);
    __shared__ ushort_t sA[128*32];
    __shared__ ushort_t sB[64*32];
    int tid = threadIdx.x, w = tid >> 6, l = tid & 63;
    long m0 = (long)blockIdx.x * 128;
    f32x4 acc[2][4] = {};
    int lr = l >> 2, lk = (l & 3) * 8;
    const ushort_t* gA = xc + (m0 + w*16 + lr)*768 + lk;
    const ushort_t* gB = wT + ((long)(w*16 + lr))*768 + lk;
    ushort_t* lA = &sA[w*16*32];
    ushort_t* lB = &sB[w*16*32];
    int arow0 = w*32 + (l & 15);
    int brow = l & 15;
    int koff = (l >> 4) * 8;
    for (int kc = 0; kc < 24; kc++){
        int k0 = kc * 32;
        gload_lds16(gA + k0,           lA);
        gload_lds16(gA + k0 + 64*768,  lA + 64*32);
        gload_lds16(gB + k0,           lB);
        __syncthreads();
        bf16x8 af[2], bfv[4];
        af[0] = *(const bf16x8*)&sA[arow0*32 + koff];
        af[1] = *(const bf16x8*)&sA[(arow0+16)*32 + koff];
        #pragma unroll
        for (int nb = 0; nb < 4; nb++)
            bfv[nb] = *(const bf16x8*)&sB[(nb*16 + brow)*32 + koff];
        #pragma unroll
        for (int mb = 0; mb < 2; mb++)
            #pragma unroll
            for (int nb = 0; nb < 4; nb++)
                acc[mb][nb] = __builtin_amdgcn_mfma_f32_16x16x32_bf16(af[mb], bfv[nb], acc[mb][nb], 0, 0, 0);
        __syncthreads();
    }
    int rbase = (l >> 4) * 4, cl = l & 15;
    #pragma unroll
    for (int mb = 0; mb < 2; mb++)
        #pragma unroll
        for (int nb = 0; nb < 4; nb++){
            int col = nb*16 + cl;
            if (col < 56){
                long row = m0 + w*32 + mb*16 + rbase;
                #pragma unroll
                for (int r = 0; r < 4; r++)
                    xdbl[(row + r)*56 + col] = acc[mb][nb][r];
            }
        }
}

// ---------------- k7: chunk-parallel selective scan (pass 1) --------------
// Thread = (d, half): lane pair splits the 16 states (8 each) so per-thread
// state fits in VGPRs (R3 post-mortem: 16-state/thread spilled -> 12.5 GB
// scratch traffic). dt dot split 12+12, combined via shfl_xor(1); xc/z
// loads split by parity and exchanged via shuffle.
__global__ __launch_bounds__(256, 2) void k_scan(char* ws){
    const ushort_t* xc = (const ushort_t*)(ws + O_XC);
    const ushort_t* wz = (const ushort_t*)(ws + O_Z);      // silu(z)
    const float* xdbl = (const float*)(ws + O_XDBL);
    const float* Ag = (const float*)(ws + O_A);            // -exp(A_log)*log2e
    const float* Dsk = (const float*)(ws + O_DSKIP);
    const float* Wdt = (const float*)(ws + O_WDT);
    const float* dtb = (const float*)(ws + O_DTB);
    float* FX = (float*)(ws + O_FX);
    int tid = threadIdx.x;
    int half = tid & 1, p = tid >> 1;          // 128 d per block
    int d = blockIdx.x * 128 + p;
    int c = blockIdx.y, b = blockIdx.z;
    long row0 = (long)b * L_ + (long)c * CL;

    float wdt[12];
    #pragma unroll
    for (int k = 0; k < 12; k++) wdt[k] = Wdt[(half*12 + k)*768 + d];
    float dbias = half ? 0.f : dtb[d];
    float Av[8];
    #pragma unroll
    for (int s = 0; s < 8; s++) Av[s] = Ag[d*16 + half*8 + s];
    float Dsel = half ? 0.f : Dsk[d];

    __shared__ float sXD[CL*56];               // chunk's xdbl rows (28 KB)
    {
        const f32x4* src = (const f32x4*)(xdbl + row0*56);
        f32x4* dst = (f32x4*)sXD;
        #pragma unroll
        for (int i = 0; i < 7; i++) dst[tid + i*256] = src[tid + i*256];
    }
    __syncthreads();

    float h[8], q[8], G[8];
    #pragma unroll
    for (int s = 0; s < 8; s++){ h[s] = 0.f; q[s] = 1.f; G[s] = 0.f; }
    float ysum = 0.f;

    const ushort_t* gx = half ? wz : xc;       // parity-split streams
    #pragma unroll 2
    for (int t = 0; t < CL; t++){
        const float* xd = &sXD[t*56];
        float dt_p = dbias;
        #pragma unroll
        for (int j = 0; j < 3; j++){
            f32x4 v = *(const f32x4*)&xd[half*12 + j*4];
            dt_p += v[0]*wdt[j*4] + v[1]*wdt[j*4+1] + v[2]*wdt[j*4+2] + v[3]*wdt[j*4+3];
        }
        float dtv = dt_p + __shfl_xor(dt_p, 1);
        dtv = (dtv > 20.f) ? dtv : 0.69314718056f * __log2f(1.f + exp2f(dtv * 1.4426950409f));
        u32 mine = gx[(row0 + t)*768 + d];
        u32 other = (u32)__shfl_xor((int)mine, 1);
        float xcv = bf2f((ushort_t)(half ? other : mine));
        float wzv = bf2f((ushort_t)(half ? mine : other));
        float u = dtv * xcv;
        f32x4 Bv0 = *(const f32x4*)&xd[24 + half*8];
        f32x4 Bv1 = *(const f32x4*)&xd[28 + half*8];
        f32x4 Cv0 = *(const f32x4*)&xd[40 + half*8];
        f32x4 Cv1 = *(const f32x4*)&xd[44 + half*8];
        float yp = 0.f;
        #pragma unroll
        for (int s = 0; s < 8; s++){
            float Bs = (s < 4) ? Bv0[s&3] : Bv1[s&3];
            float Cs = (s < 4) ? Cv0[s&3] : Cv1[s&3];
            float dA = exp2f(dtv * Av[s]);
            h[s] = dA*h[s] + u*Bs;
            float Cw = Cs * wzv;
            yp += h[s] * Cw;
            q[s] *= dA;
            G[s] += q[s] * Cw;
        }
        ysum += yp + xcv * Dsel * wzv;
    }
    ysum += __shfl_xor(ysum, 1);
    long fb = ((long)(b*NCHUNK + c)*49)*768 + d;
    if (!half) FX[fb] = ysum;
    #pragma unroll
    for (int s = 0; s < 8; s++){
        int sg = half*8 + s;
        FX[fb + (1+sg)*768]  = h[s];
        FX[fb + (17+sg)*768] = q[s];
        FX[fb + (33+sg)*768] = G[s];
    }
}

// ---------------- k8: scan pass 2 — stitch chunks (thread per (b,d,s)) ----
// Per-s recurrence Hrun[s] = H[s] + q[s]*Hrun[s] is independent across s;
// ys contributions reduced over s in LDS. 384 blocks (was 24 -> latency-bound).
__global__ __launch_bounds__(256) void k_fix(char* ws){
    const float* FX = (const float*)(ws + O_FX);
    float* ymean = (float*)(ws + O_YMEAN);
    int tid = threadIdx.x;
    int dl = tid & 15, s = tid >> 4;
    int d = blockIdx.x * 16 + dl;
    int b = blockIdx.y;
    float Hrun = 0.f, ys = 0.f;
    for (int c = 0; c < NCHUNK; c++){
        long fb = ((long)(b*NCHUNK + c)*49)*768 + d;
        float Gs = FX[fb + (33+s)*768];
        float Hs = FX[fb + (1+s)*768];
        float qs = FX[fb + (17+s)*768];
        ys += Hrun * Gs;
        if (s == 0) ys += FX[fb];
        Hrun = Hs + qs * Hrun;
    }
    __shared__ float sR[256];
    sR[tid] = ys;
    __syncthreads();
    #pragma unroll
    for (int st = 8; st >= 1; st >>= 1){
        if (s < st) sR[tid] += sR[tid + st*16];
        __syncthreads();
    }
    if (s == 0) ymean[b*768 + d] = sR[dl] * (1.f/L_);
}

// ---------------- k9: head part 1: pooled -> h = pooled@W_fc + b_fc ------
__global__ __launch_bounds__(256) void k_head1(char* ws){
    const float* ymean = (const float*)(ws + O_YMEAN);
    const float* xmean = (const float*)(ws + O_XMEAN);
    const float* Wout = (const float*)(ws + O_WOUT);
    const float* Wfc = (const float*)(ws + O_WFC);
    const float* bfc = (const float*)(ws + O_BFC);
    float* hbuf = (float*)(ws + O_H);
    int b = blockIdx.x, tid = threadIdx.x;
    __shared__ float sY[768];
    __shared__ float sP[384];
    sY[tid] = ymean[b*768 + tid];
    sY[tid+256] = ymean[b*768 + tid + 256];
    sY[tid+512] = ymean[b*768 + tid + 512];
    __syncthreads();
    for (int d = tid; d < 384; d += 256){
        float v = xmean[b*384 + d];
        for (int i = 0; i < 768; i++) v += sY[i] * Wout[i*384 + d];
        sP[d] = v;
    }
    __syncthreads();
    float v = bfc[tid];
    for (int dd = 0; dd < 384; dd++) v += sP[dd] * Wfc[dd*256 + tid];
    hbuf[b*256 + tid] = v;
}

// ---------------- k10: head part 2: batchnorm + relu + classifier --------
__global__ __launch_bounds__(384) void k_head2(char* ws, void* out){
    const int flag = *(const int*)(ws + O_FLAG);
    const float* hbuf = (const float*)(ws + O_H);
    const float* gam = (const float*)(ws + O_GAM);
    const float* bet = (const float*)(ws + O_BET);
    const float* Wcls = (const float*)(ws + O_WCLS);
    const float* bcls = (const float*)(ws + O_BCLS);
    int tid = threadIdx.x;
    __shared__ float sH[8*256];
    if (tid < 256){
        float hv[8]; float mu = 0.f;
        #pragma unroll
        for (int b = 0; b < 8; b++){ hv[b] = hbuf[b*256 + tid]; mu += hv[b]; }
        mu *= 0.125f;
        float var = 0.f;
        #pragma unroll
        for (int b = 0; b < 8; b++){ float dv = hv[b]-mu; var += dv*dv; }
        var *= 0.125f;
        float rs = rsqrtf(var + 1e-5f);
        #pragma unroll
        for (int b = 0; b < 8; b++){
            float t = (hv[b]-mu)*rs*gam[tid] + bet[tid];
            sH[b*256 + tid] = t > 0.f ? t : 0.f;
        }
    }
    __syncthreads();
    if (tid < 320){
        int b = tid / 40, c = tid % 40;
        float acc = bcls[c];
        for (int j = 0; j < 256; j++) acc += sH[b*256 + j] * Wcls[j*40 + c];
        if (flag) ((ushort_t*)out)[b*40 + c] = f2bf(acc);
        else      ((float*)out)[b*40 + c] = acc;
    }
}

// ---------------- launch ----------------
extern "C" void kernel_launch(void* const* d_in, const int* in_sizes, int n_in,
                              void* d_out, int out_size, void* d_ws, size_t ws_size,
                              hipStream_t stream){
    (void)in_sizes; (void)n_in; (void)out_size; (void)ws_size;
    char* ws = (char*)d_ws;
    Ptrs ps;
    for (int i = 0; i < 17; i++) ps.p[i] = d_in[i];

    k_detect<<<1, 256, 0, stream>>>(d_in[0], ws);
    k_prep<<<(unsigned)((N_PREP + 255) / 256), 256, 0, stream>>>(ps, ws);
    k_rmsnorm<<<ML_, 128, 0, stream>>>(d_in[0], ws);
    k_xmean<<<dim3(8, 3, 16), 256, 0, stream>>>(d_in[0], ws);
    k_gemm1<<<dim3(ML_/128, 12), 256, 0, stream>>>(ws);
    k_conv<<<dim3(3, L_/8, B_), 256, 0, stream>>>(ws);
    k_xproj<<<ML_/128, 256, 0, stream>>>(ws);
    k_scan<<<dim3(6, NCHUNK, B_), 256, 0, stream>>>(ws);
    k_fix<<<dim3(48, B_), 256, 0, stream>>>(ws);
    k_head1<<<B_, 256, 0, stream>>>(ws);
    k_head2<<<1, 384, 0, stream>>>(ws, d_out);
}

// Round 5
// 569.309 us; speedup vs baseline: 6.5171x; 1.0032x over previous
//
#include <hip/hip_runtime.h>

typedef unsigned short ushort_t;
typedef unsigned int u32;
typedef float f32x4 __attribute__((ext_vector_type(4)));
typedef float f32x2 __attribute__((ext_vector_type(2)));
typedef __bf16 bf16x8 __attribute__((ext_vector_type(8)));

#define B_ 8
#define L_ 4096
#define D_ 384
#define DI_ 768
#define S_ 16
#define NC_ 40
#define ML_ (B_*L_)   // 32768 rows
#define NCHUNK 32
#define CL 128        // chunk length (L_/NCHUNK)

// ---------------- workspace layout (bytes) ----------------
// ~154 MB total. Aliasing:
//   XN lives in XC region (dead after gemm1, before conv writes XC);
//   XDBL lives at start of XP region (XP dead after conv);
//   FX (chunk summaries, 38.5 MB) lives in XP region after XDBL.
constexpr size_t au(size_t x){ return (x + 255) & ~size_t(255); }
constexpr size_t O_FLAG = 0;                                   // int
constexpr size_t O_LNW  = 256;                                 // 384 f32
constexpr size_t O_CONVW= au(O_LNW  + 384*4);                  // 3072 f32
constexpr size_t O_CONVB= au(O_CONVW+ 3072*4);                 // 768 f32
constexpr size_t O_WDT  = au(O_CONVB+ 768*4);                  // 18432 f32
constexpr size_t O_DTB  = au(O_WDT  + 18432*4);                // 768 f32
constexpr size_t O_A    = au(O_DTB  + 768*4);                  // 12288 f32 (A = -exp(A_log)*log2e)
constexpr size_t O_DSKIP= au(O_A    + 12288*4);                // 768 f32
constexpr size_t O_WOUT = au(O_DSKIP+ 768*4);                  // 294912 f32
constexpr size_t O_WFC  = au(O_WOUT + 294912*4);               // 98304 f32
constexpr size_t O_BFC  = au(O_WFC  + 98304*4);                // 256 f32
constexpr size_t O_GAM  = au(O_BFC  + 256*4);
constexpr size_t O_BET  = au(O_GAM  + 256*4);
constexpr size_t O_WCLS = au(O_BET  + 256*4);                  // 10240 f32
constexpr size_t O_BCLS = au(O_WCLS + 10240*4);                // 40 f32
constexpr size_t O_XMEAN= au(O_BCLS + 40*4);                   // 8*384 f32 (atomic acc, zeroed in prep)
constexpr size_t O_YMEAN= au(O_XMEAN+ 3072*4);                 // 8*768 f32
constexpr size_t O_H    = au(O_YMEAN+ 6144*4);                 // 8*256 f32
constexpr size_t O_WINT = au(O_H    + 2048*4);                 // W_in^T  [1536][384] bf16
constexpr size_t O_WXT  = au(O_WINT + (size_t)589824*2);       // W_xproj^T padded [64][768] bf16
constexpr size_t O_XP   = au(O_WXT  + (size_t)49152*2);        // [32768][768] bf16
constexpr size_t O_XDBL = O_XP;                                // alias: [32768][56] f32 (after conv)
constexpr size_t O_FX   = au(O_XDBL + (size_t)ML_*56*4);       // [b][c][49][768] f32 chunk summaries
constexpr size_t FX_SZ  = (size_t)B_*NCHUNK*49*768*4;          // 38.5 MB
constexpr size_t O_Z    = au(O_XP   + (size_t)ML_*768*2);      // [32768][768] bf16 (holds silu(z))
constexpr size_t O_XCU  = au(O_Z    + (size_t)ML_*768*2);      // union region, 50.3 MB
constexpr size_t O_XN   = O_XCU;                               // [32768][384] bf16 (dead after gemm1)
constexpr size_t O_XC   = O_XCU;                               // [32768][768] bf16
constexpr size_t WS_NEED= O_XCU + (size_t)ML_*768*2;           // ~154 MB
static_assert(O_FX + FX_SZ <= O_Z, "FX must fit in dead XP tail");

// ---------------- helpers ----------------
__device__ inline float bf2f(ushort_t u){ return __uint_as_float(((u32)u) << 16); }
__device__ inline ushort_t f2bf(float f){
    u32 x = __float_as_uint(f);
    u32 r = (x + 0x7fffu + ((x >> 16) & 1u)) >> 16;   // RNE
    return (ushort_t)r;
}
__device__ inline float ldf(const void* p, long i, int flag){
    return flag ? bf2f(((const ushort_t*)p)[i]) : ((const float*)p)[i];
}
__device__ inline ushort_t ldbf(const void* p, long i, int flag){
    return flag ? ((const ushort_t*)p)[i] : f2bf(((const float*)p)[i]);
}
__device__ inline float sigm(float v){ return 1.f / (1.f + __expf(-v)); }

__device__ inline void gload_lds16(const void* g, void* l){
    __builtin_amdgcn_global_load_lds(
        (const __attribute__((address_space(1))) u32*)g,
        (__attribute__((address_space(3))) u32*)l, 16, 0, 0);
}

struct Ptrs { const void* p[17]; };

// ---------------- k0: dtype detect ----------------
__global__ void k_detect(const void* x, char* ws){
    __shared__ float s[256];
    int tid = threadIdx.x;
    s[tid] = fabsf(bf2f(((const ushort_t*)x)[tid]));
    __syncthreads();
    for (int st = 128; st > 0; st >>= 1){
        if (tid < st) s[tid] = fmaxf(s[tid], s[tid + st]);
        __syncthreads();
    }
    if (tid == 0) *(int*)(ws + O_FLAG) = (s[0] < 1e4f) ? 1 : 0;
}

// ---------------- k1: weight prep ----------------
#define N_PREP 1082792L
__global__ __launch_bounds__(256) void k_prep(Ptrs ps, char* ws){
    const int flag = *(const int*)(ws + O_FLAG);
    long o = (long)blockIdx.x * 256 + threadIdx.x;
    if (o < 384){ ((float*)(ws+O_LNW))[o]  = ldf(ps.p[1],o,flag); return; }  o -= 384;
    if (o < 3072){ ((float*)(ws+O_CONVW))[o]= ldf(ps.p[3],o,flag); return; } o -= 3072;
    if (o < 768){ ((float*)(ws+O_CONVB))[o]= ldf(ps.p[4],o,flag); return; }  o -= 768;
    if (o < 18432){ ((float*)(ws+O_WDT))[o]= ldf(ps.p[6],o,flag); return; }  o -= 18432;
    if (o < 768){ ((float*)(ws+O_DTB))[o]  = ldf(ps.p[7],o,flag); return; }  o -= 768;
    if (o < 768){ ((float*)(ws+O_DSKIP))[o]= ldf(ps.p[9],o,flag); return; }  o -= 768;
    if (o < 294912){ ((float*)(ws+O_WOUT))[o]= ldf(ps.p[10],o,flag); return; } o -= 294912;
    if (o < 98304){ ((float*)(ws+O_WFC))[o]= ldf(ps.p[11],o,flag); return; } o -= 98304;
    if (o < 256){ ((float*)(ws+O_BFC))[o]  = ldf(ps.p[12],o,flag); return; } o -= 256;
    if (o < 256){ ((float*)(ws+O_GAM))[o]  = ldf(ps.p[13],o,flag); return; } o -= 256;
    if (o < 256){ ((float*)(ws+O_BET))[o]  = ldf(ps.p[14],o,flag); return; } o -= 256;
    if (o < 10240){ ((float*)(ws+O_WCLS))[o]= ldf(ps.p[15],o,flag); return; } o -= 10240;
    if (o < 40){ ((float*)(ws+O_BCLS))[o]  = ldf(ps.p[16],o,flag); return; } o -= 40;
    // A = -exp(A_log) * log2(e)   (scan uses exp2)
    if (o < 12288){ ((float*)(ws+O_A))[o]  = -__expf(ldf(ps.p[8],o,flag)) * 1.4426950408889634f; return; } o -= 12288;
    if (o < 589824){                     // W_in [384,1536] -> WinT [1536][384]
        long n = o / 384, k = o % 384;
        ((ushort_t*)(ws+O_WINT))[o] = ldbf(ps.p[2], k*1536 + n, flag); return;
    } o -= 589824;
    if (o < 49152){                      // W_xproj [768,56] -> WxT [64][768], zero-pad n>=56
        long n = o / 768, k = o % 768;
        ((ushort_t*)(ws+O_WXT))[o] = (n < 56) ? ldbf(ps.p[5], k*56 + n, flag) : (ushort_t)0;
        return;
    } o -= 49152;
    if (o < 3072){ ((float*)(ws+O_XMEAN))[o] = 0.f; return; }
}

// ---------------- k2: RMSNorm -> xn (bf16) ----------------
__global__ __launch_bounds__(128) void k_rmsnorm(const void* x, char* ws){
    const int flag = *(const int*)(ws + O_FLAG);
    const float* lnw = (const float*)(ws + O_LNW);
    ushort_t* xn = (ushort_t*)(ws + O_XN);
    long row = blockIdx.x;
    int tid = threadIdx.x;
    float v[3];
    if (flag){
        const ushort_t* xb = (const ushort_t*)x;
        #pragma unroll
        for (int c = 0; c < 3; c++) v[c] = bf2f(xb[row*384 + tid + c*128]);
    } else {
        const float* xf = (const float*)x;
        #pragma unroll
        for (int c = 0; c < 3; c++) v[c] = xf[row*384 + tid + c*128];
    }
    __shared__ float red[128];
    red[tid] = v[0]*v[0] + v[1]*v[1] + v[2]*v[2];
    __syncthreads();
    for (int st = 64; st > 0; st >>= 1){
        if (tid < st) red[tid] += red[tid + st];
        __syncthreads();
    }
    float scale = rsqrtf(red[0] * (1.f/384.f) + 1e-5f);
    #pragma unroll
    for (int c = 0; c < 3; c++)
        xn[row*384 + tid + c*128] = f2bf(v[c] * scale * lnw[tid + c*128]);
}

// ---------------- k3: xmean[b,d] = mean_L x ----------------
__global__ __launch_bounds__(256) void k_xmean(const void* x, char* ws){
    const int flag = *(const int*)(ws + O_FLAG);
    float* xmean = (float*)(ws + O_XMEAN);
    int b = blockIdx.x, d0 = blockIdx.y*128, l0 = blockIdx.z*256;
    int tid = threadIdx.x, dl = tid & 127, lh = tid >> 7;
    float acc = 0.f;
    if (flag){
        const ushort_t* xb = (const ushort_t*)x;
        for (int l = l0 + lh; l < l0 + 256; l += 2)
            acc += bf2f(xb[((long)b*L_ + l)*384 + d0 + dl]);
    } else {
        const float* xf = (const float*)x;
        for (int l = l0 + lh; l < l0 + 256; l += 2)
            acc += xf[((long)b*L_ + l)*384 + d0 + dl];
    }
    __shared__ float s[256];
    s[tid] = acc; __syncthreads();
    if (tid < 128)
        atomicAdd(&xmean[b*384 + d0 + dl], (s[tid] + s[tid+128]) * (1.f/L_));
}

// ---------------- k4: GEMM1  xn @ W_in -> xp | silu(z) ---------
__global__ __launch_bounds__(256) void k_gemm1(char* ws){
    const ushort_t* xn = (const ushort_t*)(ws + O_XN);
    const ushort_t* wT = (const ushort_t*)(ws + O_WINT);
    ushort_t* xp = (ushort_t*)(ws + O_XP);
    ushort_t* zz = (ushort_t*)(ws + O_Z);
    __shared__ ushort_t sA[128*32];
    __shared__ ushort_t sB[128*32];
    int tid = threadIdx.x, w = tid >> 6, l = tid & 63;
    long m0 = (long)blockIdx.x * 128;
    int n0 = blockIdx.y * 128;
    f32x4 acc[4][4] = {};
    int lr = l >> 2, lk = (l & 3) * 8;
    const ushort_t* gA = xn + (m0 + w*16 + lr)*384 + lk;
    const ushort_t* gB = wT + ((long)(n0 + w*16 + lr))*384 + lk;
    ushort_t* lA = &sA[w*16*32];
    ushort_t* lB = &sB[w*16*32];
    int wm = w & 1, wn = w >> 1;
    int arow = wm*64 + (l & 15);
    int brow = wn*64 + (l & 15);
    int koff = (l >> 4) * 8;
    for (int kc = 0; kc < 12; kc++){
        int k0 = kc * 32;
        gload_lds16(gA + k0,           lA);
        gload_lds16(gA + k0 + 64*384,  lA + 64*32);
        gload_lds16(gB + k0,           lB);
        gload_lds16(gB + k0 + 64*384,  lB + 64*32);
        __syncthreads();
        bf16x8 af[4], bfv[4];
        #pragma unroll
        for (int i = 0; i < 4; i++){
            af[i]  = *(const bf16x8*)&sA[(arow + i*16)*32 + koff];
            bfv[i] = *(const bf16x8*)&sB[(brow + i*16)*32 + koff];
        }
        #pragma unroll
        for (int mb = 0; mb < 4; mb++)
            #pragma unroll
            for (int nb = 0; nb < 4; nb++)
                acc[mb][nb] = __builtin_amdgcn_mfma_f32_16x16x32_bf16(af[mb], bfv[nb], acc[mb][nb], 0, 0, 0);
        __syncthreads();
    }
    ushort_t* outp; int nc0; bool isz;
    if (n0 < 768){ outp = xp; nc0 = n0; isz = false; }
    else { outp = zz; nc0 = n0 - 768; isz = true; }
    int rbase = (l >> 4) * 4, cl = l & 15;
    #pragma unroll
    for (int mb = 0; mb < 4; mb++)
        #pragma unroll
        for (int nb = 0; nb < 4; nb++){
            long row = m0 + wm*64 + mb*16 + rbase;
            int col = nc0 + wn*64 + nb*16 + cl;
            #pragma unroll
            for (int r = 0; r < 4; r++){
                float v = acc[mb][nb][r];
                if (isz) v = v * sigm(v);        // fused silu for z
                outp[(row + r)*768 + col] = f2bf(v);
            }
        }
}

// ---------------- k5: causal depthwise conv K=4 + SiLU ----------------
__global__ __launch_bounds__(256) void k_conv(char* ws){
    const ushort_t* xp = (const ushort_t*)(ws + O_XP);
    ushort_t* xc = (ushort_t*)(ws + O_XC);
    const float* cw = (const float*)(ws + O_CONVW);
    const float* cb = (const float*)(ws + O_CONVB);
    int d = blockIdx.x*256 + threadIdx.x;
    int t0 = blockIdx.y * 8;
    int b = blockIdx.z;
    long rbase = (long)b * L_;
    float w0 = cw[d*4], w1 = cw[d*4+1], w2 = cw[d*4+2], w3 = cw[d*4+3];
    float bias = cb[d];
    float xv[11];
    #pragma unroll
    for (int i = 0; i < 11; i++){
        int t = t0 - 3 + i;
        xv[i] = (t >= 0) ? bf2f(xp[(rbase + t)*768 + d]) : 0.f;
    }
    #pragma unroll
    for (int tt = 0; tt < 8; tt++){
        float v = bias + xv[tt]*w0 + xv[tt+1]*w1 + xv[tt+2]*w2 + xv[tt+3]*w3;
        v = v * sigm(v);
        xc[(rbase + t0 + tt)*768 + d] = f2bf(v);
    }
}

// ---------------- k6: xproj  xc @ W_xproj -> x_dbl[32768,56] ----
__global__ __launch_bounds__(256) void k_xproj(char* ws){
    const ushort_t* xc = (const ushort_t*)(ws + O_XC);
    const ushort_t* wT = (const ushort_t*)(ws + O_WXT);
    float* xdbl = (float*)(ws + O_XDBL);
    __shared__ ushort_t sA[128*32];
    __shared__ ushort_t sB[64*32];
    int tid = threadIdx.x, w = tid >> 6, l = tid & 63;
    long m0 = (long)blockIdx.x * 128;
    f32x4 acc[2][4] = {};
    int lr = l >> 2, lk = (l & 3) * 8;
    const ushort_t* gA = xc + (m0 + w*16 + lr)*768 + lk;
    const ushort_t* gB = wT + ((long)(w*16 + lr))*768 + lk;
    ushort_t* lA = &sA[w*16*32];
    ushort_t* lB = &sB[w*16*32];
    int arow0 = w*32 + (l & 15);
    int brow = l & 15;
    int koff = (l >> 4) * 8;
    for (int kc = 0; kc < 24; kc++){
        int k0 = kc * 32;
        gload_lds16(gA + k0,           lA);
        gload_lds16(gA + k0 + 64*768,  lA + 64*32);
        gload_lds16(gB + k0,           lB);
        __syncthreads();
        bf16x8 af[2], bfv[4];
        af[0] = *(const bf16x8*)&sA[arow0*32 + koff];
        af[1] = *(const bf16x8*)&sA[(arow0+16)*32 + koff];
        #pragma unroll
        for (int nb = 0; nb < 4; nb++)
            bfv[nb] = *(const bf16x8*)&sB[(nb*16 + brow)*32 + koff];
        #pragma unroll
        for (int mb = 0; mb < 2; mb++)
            #pragma unroll
            for (int nb = 0; nb < 4; nb++)
                acc[mb][nb] = __builtin_amdgcn_mfma_f32_16x16x32_bf16(af[mb], bfv[nb], acc[mb][nb], 0, 0, 0);
        __syncthreads();
    }
    int rbase = (l >> 4) * 4, cl = l & 15;
    #pragma unroll
    for (int mb = 0; mb < 2; mb++)
        #pragma unroll
        for (int nb = 0; nb < 4; nb++){
            int col = nb*16 + cl;
            if (col < 56){
                long row = m0 + w*32 + mb*16 + rbase;
                #pragma unroll
                for (int r = 0; r < 4; r++)
                    xdbl[(row + r)*56 + col] = acc[mb][nb][r];
            }
        }
}

// ---------------- k7: chunk-parallel selective scan (pass 1) --------------
// Thread = (d, half): 8 states each as float2[4] (targets v_pk_*_f32).
// No LDS, no barriers: xdbl rows read directly (L1-resident, block-uniform
// base); exp2 via __builtin (1 inst); D-skip term hoisted out of the loop.
__global__ __launch_bounds__(256, 4) void k_scan(char* ws){
    const ushort_t* xc = (const ushort_t*)(ws + O_XC);
    const ushort_t* wz = (const ushort_t*)(ws + O_Z);      // silu(z)
    const float* xdbl = (const float*)(ws + O_XDBL);
    const float* Ag = (const float*)(ws + O_A);            // -exp(A_log)*log2e
    const float* Dsk = (const float*)(ws + O_DSKIP);
    const float* Wdt = (const float*)(ws + O_WDT);
    const float* dtb = (const float*)(ws + O_DTB);
    float* FX = (float*)(ws + O_FX);
    int tid = threadIdx.x;
    int half = tid & 1, p = tid >> 1;          // 128 d per block, pair = lanes 2k,2k+1
    int d = blockIdx.x * 128 + p;
    int c = blockIdx.y, b = blockIdx.z;
    long row0 = (long)b * L_ + (long)c * CL;

    f32x2 wdt2[6];
    #pragma unroll
    for (int k = 0; k < 6; k++){
        wdt2[k][0] = Wdt[(half*12 + 2*k    )*768 + d];
        wdt2[k][1] = Wdt[(half*12 + 2*k + 1)*768 + d];
    }
    float dbias = half ? 0.f : dtb[d];
    f32x2 Av2[4];
    #pragma unroll
    for (int j = 0; j < 4; j++){
        Av2[j][0] = Ag[d*16 + half*8 + 2*j];
        Av2[j][1] = Ag[d*16 + half*8 + 2*j + 1];
    }
    float Dv = Dsk[d];

    f32x2 h2[4], q2[4], G2[4];
    #pragma unroll
    for (int j = 0; j < 4; j++){
        h2[j] = f32x2{0.f, 0.f}; G2[j] = f32x2{0.f, 0.f}; q2[j] = f32x2{1.f, 1.f};
    }
    f32x2 ysum2 = {0.f, 0.f};
    float sdw = 0.f;

    const f32x4* xrow = (const f32x4*)(xdbl + row0*56);   // 14 vec4 per row
    #pragma unroll 2
    for (int t = 0; t < CL; t++){
        const f32x4* xd4 = xrow + t*14;
        // dt partial over this half's 12 dt_r cols (6 pk_fma)
        f32x2 acc2 = {dbias, 0.f};
        #pragma unroll
        for (int j = 0; j < 3; j++){
            f32x4 v = xd4[half*3 + j];
            acc2 += f32x2{v[0], v[1]} * wdt2[2*j];
            acc2 += f32x2{v[2], v[3]} * wdt2[2*j + 1];
        }
        float dt_p = acc2[0] + acc2[1];
        float dtv = dt_p + __shfl_xor(dt_p, 1);
        // softplus: ln(1+e^x) = log2(1+2^(x*log2e))*ln2
        float e = __builtin_amdgcn_exp2f(dtv * 1.4426950408889634f);
        float sp = 0.69314718055994531f * __builtin_amdgcn_logf(1.f + e);
        dtv = (dtv > 20.f) ? dtv : sp;

        long rr = (row0 + t)*768 + d;
        float xcv = bf2f(xc[rr]);
        float wzv = bf2f(wz[rr]);
        float u = dtv * xcv;
        f32x2 u2 = {u, u}, wz2 = {wzv, wzv}, dtv2 = {dtv, dtv};
        f32x4 Bva = xd4[6 + half*2], Bvb = xd4[7 + half*2];
        f32x4 Cva = xd4[10 + half*2], Cvb = xd4[11 + half*2];
        #pragma unroll
        for (int j = 0; j < 4; j++){
            f32x2 Bj = (j < 2) ? f32x2{Bva[2*j], Bva[2*j+1]} : f32x2{Bvb[2*j-4], Bvb[2*j-3]};
            f32x2 Cj = (j < 2) ? f32x2{Cva[2*j], Cva[2*j+1]} : f32x2{Cvb[2*j-4], Cvb[2*j-3]};
            f32x2 arg = dtv2 * Av2[j];
            f32x2 dA;
            dA[0] = __builtin_amdgcn_exp2f(arg[0]);
            dA[1] = __builtin_amdgcn_exp2f(arg[1]);
            h2[j] = dA * h2[j] + u2 * Bj;
            f32x2 Cw = Cj * wz2;
            ysum2 += h2[j] * Cw;
            q2[j] = q2[j] * dA;
            G2[j] += q2[j] * Cw;
        }
        sdw += xcv * wzv;
    }
    float ys = ysum2[0] + ysum2[1] + (half ? 0.f : Dv * sdw);
    ys += __shfl_xor(ys, 1);
    long fb = ((long)(b*NCHUNK + c)*49)*768 + d;
    if (!half) FX[fb] = ys;
    #pragma unroll
    for (int j = 0; j < 4; j++){
        int sg = half*8 + 2*j;
        FX[fb + (1+sg)*768]  = h2[j][0];  FX[fb + (2+sg)*768]  = h2[j][1];
        FX[fb + (17+sg)*768] = q2[j][0];  FX[fb + (18+sg)*768] = q2[j][1];
        FX[fb + (33+sg)*768] = G2[j][0];  FX[fb + (34+sg)*768] = G2[j][1];
    }
}

// ---------------- k8: scan pass 2 — stitch chunks (thread per (b,d,s)) ----
__global__ __launch_bounds__(256) void k_fix(char* ws){
    const float* FX = (const float*)(ws + O_FX);
    float* ymean = (float*)(ws + O_YMEAN);
    int tid = threadIdx.x;
    int dl = tid & 15, s = tid >> 4;
    int d = blockIdx.x * 16 + dl;
    int b = blockIdx.y;
    float Hrun = 0.f, ys = 0.f;
    for (int c = 0; c < NCHUNK; c++){
        long fb = ((long)(b*NCHUNK + c)*49)*768 + d;
        float Gs = FX[fb + (33+s)*768];
        float Hs = FX[fb + (1+s)*768];
        float qs = FX[fb + (17+s)*768];
        ys += Hrun * Gs;
        if (s == 0) ys += FX[fb];
        Hrun = Hs + qs * Hrun;
    }
    __shared__ float sR[256];
    sR[tid] = ys;
    __syncthreads();
    #pragma unroll
    for (int st = 8; st >= 1; st >>= 1){
        if (s < st) sR[tid] += sR[tid + st*16];
        __syncthreads();
    }
    if (s == 0) ymean[b*768 + d] = sR[dl] * (1.f/L_);
}

// ---------------- k9: head part 1: pooled -> h = pooled@W_fc + b_fc ------
__global__ __launch_bounds__(256) void k_head1(char* ws){
    const float* ymean = (const float*)(ws + O_YMEAN);
    const float* xmean = (const float*)(ws + O_XMEAN);
    const float* Wout = (const float*)(ws + O_WOUT);
    const float* Wfc = (const float*)(ws + O_WFC);
    const float* bfc = (const float*)(ws + O_BFC);
    float* hbuf = (float*)(ws + O_H);
    int b = blockIdx.x, tid = threadIdx.x;
    __shared__ float sY[768];
    __shared__ float sP[384];
    sY[tid] = ymean[b*768 + tid];
    sY[tid+256] = ymean[b*768 + tid + 256];
    sY[tid+512] = ymean[b*768 + tid + 512];
    __syncthreads();
    for (int d = tid; d < 384; d += 256){
        float v = xmean[b*384 + d];
        for (int i = 0; i < 768; i++) v += sY[i] * Wout[i*384 + d];
        sP[d] = v;
    }
    __syncthreads();
    float v = bfc[tid];
    for (int dd = 0; dd < 384; dd++) v += sP[dd] * Wfc[dd*256 + tid];
    hbuf[b*256 + tid] = v;
}

// ---------------- k10: head part 2: batchnorm + relu + classifier --------
__global__ __launch_bounds__(384) void k_head2(char* ws, void* out){
    const int flag = *(const int*)(ws + O_FLAG);
    const float* hbuf = (const float*)(ws + O_H);
    const float* gam = (const float*)(ws + O_GAM);
    const float* bet = (const float*)(ws + O_BET);
    const float* Wcls = (const float*)(ws + O_WCLS);
    const float* bcls = (const float*)(ws + O_BCLS);
    int tid = threadIdx.x;
    __shared__ float sH[8*256];
    if (tid < 256){
        float hv[8]; float mu = 0.f;
        #pragma unroll
        for (int b = 0; b < 8; b++){ hv[b] = hbuf[b*256 + tid]; mu += hv[b]; }
        mu *= 0.125f;
        float var = 0.f;
        #pragma unroll
        for (int b = 0; b < 8; b++){ float dv = hv[b]-mu; var += dv*dv; }
        var *= 0.125f;
        float rs = rsqrtf(var + 1e-5f);
        #pragma unroll
        for (int b = 0; b < 8; b++){
            float t = (hv[b]-mu)*rs*gam[tid] + bet[tid];
            sH[b*256 + tid] = t > 0.f ? t : 0.f;
        }
    }
    __syncthreads();
    if (tid < 320){
        int b = tid / 40, c = tid % 40;
        float acc = bcls[c];
        for (int j = 0; j < 256; j++) acc += sH[b*256 + j] * Wcls[j*40 + c];
        if (flag) ((ushort_t*)out)[b*40 + c] = f2bf(acc);
        else      ((float*)out)[b*40 + c] = acc;
    }
}

// ---------------- launch ----------------
extern "C" void kernel_launch(void* const* d_in, const int* in_sizes, int n_in,
                              void* d_out, int out_size, void* d_ws, size_t ws_size,
                              hipStream_t stream){
    (void)in_sizes; (void)n_in; (void)out_size; (void)ws_size;
    char* ws = (char*)d_ws;
    Ptrs ps;
    for (int i = 0; i < 17; i++) ps.p[i] = d_in[i];

    k_detect<<<1, 256, 0, stream>>>(d_in[0], ws);
    k_prep<<<(unsigned)((N_PREP + 255) / 256), 256, 0, stream>>>(ps, ws);
    k_rmsnorm<<<ML_, 128, 0, stream>>>(d_in[0], ws);
    k_xmean<<<dim3(8, 3, 16), 256, 0, stream>>>(d_in[0], ws);
    k_gemm1<<<dim3(ML_/128, 12), 256, 0, stream>>>(ws);
    k_conv<<<dim3(3, L_/8, B_), 256, 0, stream>>>(ws);
    k_xproj<<<ML_/128, 256, 0, stream>>>(ws);
    k_scan<<<dim3(6, NCHUNK, B_), 256, 0, stream>>>(ws);
    k_fix<<<dim3(48, B_), 256, 0, stream>>>(ws);
    k_head1<<<B_, 256, 0, stream>>>(ws);
    k_head2<<<1, 384, 0, stream>>>(ws, d_out);
}

// Round 6
// 552.807 us; speedup vs baseline: 6.7117x; 1.0299x over previous
//
#include <hip/hip_runtime.h>

typedef unsigned short ushort_t;
typedef unsigned int u32;
typedef float f32x4 __attribute__((ext_vector_type(4)));
typedef float f32x2 __attribute__((ext_vector_type(2)));
typedef __bf16 bf16x8 __attribute__((ext_vector_type(8)));

#define B_ 8
#define L_ 4096
#define D_ 384
#define DI_ 768
#define S_ 16
#define NC_ 40
#define ML_ (B_*L_)   // 32768 rows
#define NCHUNK 32
#define CL 128        // chunk length (L_/NCHUNK)

// ---------------- workspace layout (bytes) ----------------
// ~154 MB total. Aliasing:
//   XN lives in XC region (dead after gemm1, before conv writes XC);
//   XDBL lives at start of XP region (XP dead after conv);
//   FX (chunk summaries, 38.5 MB) lives in XP region after XDBL.
constexpr size_t au(size_t x){ return (x + 255) & ~size_t(255); }
constexpr size_t O_FLAG = 0;                                   // int
constexpr size_t O_LNW  = 256;                                 // 384 f32
constexpr size_t O_CONVW= au(O_LNW  + 384*4);                  // 3072 f32
constexpr size_t O_CONVB= au(O_CONVW+ 3072*4);                 // 768 f32
constexpr size_t O_WDT  = au(O_CONVB+ 768*4);                  // 18432 f32
constexpr size_t O_DTB  = au(O_WDT  + 18432*4);                // 768 f32
constexpr size_t O_A    = au(O_DTB  + 768*4);                  // 12288 f32 (A = -exp(A_log)*log2e)
constexpr size_t O_DSKIP= au(O_A    + 12288*4);                // 768 f32
constexpr size_t O_WOUT = au(O_DSKIP+ 768*4);                  // 294912 f32
constexpr size_t O_WFC  = au(O_WOUT + 294912*4);               // 98304 f32
constexpr size_t O_BFC  = au(O_WFC  + 98304*4);                // 256 f32
constexpr size_t O_GAM  = au(O_BFC  + 256*4);
constexpr size_t O_BET  = au(O_GAM  + 256*4);
constexpr size_t O_WCLS = au(O_BET  + 256*4);                  // 10240 f32
constexpr size_t O_BCLS = au(O_WCLS + 10240*4);                // 40 f32
constexpr size_t O_XMEAN= au(O_BCLS + 40*4);                   // 8*384 f32 (atomic acc, zeroed in prep)
constexpr size_t O_YMEAN= au(O_XMEAN+ 3072*4);                 // 8*768 f32
constexpr size_t O_H    = au(O_YMEAN+ 6144*4);                 // 8*256 f32
constexpr size_t O_WINT = au(O_H    + 2048*4);                 // W_in^T  [1536][384] bf16
constexpr size_t O_WXT  = au(O_WINT + (size_t)589824*2);       // W_xproj^T padded [64][768] bf16
constexpr size_t O_XP   = au(O_WXT  + (size_t)49152*2);        // [32768][768] bf16
constexpr size_t O_XDBL = O_XP;                                // alias: [32768][56] f32 (after conv)
constexpr size_t O_FX   = au(O_XDBL + (size_t)ML_*56*4);       // [b][c][49][768] f32 chunk summaries
constexpr size_t FX_SZ  = (size_t)B_*NCHUNK*49*768*4;          // 38.5 MB
constexpr size_t O_Z    = au(O_XP   + (size_t)ML_*768*2);      // [32768][768] bf16 (holds silu(z))
constexpr size_t O_XCU  = au(O_Z    + (size_t)ML_*768*2);      // union region, 50.3 MB
constexpr size_t O_XN   = O_XCU;                               // [32768][384] bf16 (dead after gemm1)
constexpr size_t O_XC   = O_XCU;                               // [32768][768] bf16
constexpr size_t WS_NEED= O_XCU + (size_t)ML_*768*2;           // ~154 MB
static_assert(O_FX + FX_SZ <= O_Z, "FX must fit in dead XP tail");

// ---------------- helpers ----------------
__device__ inline float bf2f(ushort_t u){ return __uint_as_float(((u32)u) << 16); }
__device__ inline ushort_t f2bf(float f){
    u32 x = __float_as_uint(f);
    u32 r = (x + 0x7fffu + ((x >> 16) & 1u)) >> 16;   // RNE
    return (ushort_t)r;
}
__device__ inline float ldf(const void* p, long i, int flag){
    return flag ? bf2f(((const ushort_t*)p)[i]) : ((const float*)p)[i];
}
__device__ inline ushort_t ldbf(const void* p, long i, int flag){
    return flag ? ((const ushort_t*)p)[i] : f2bf(((const float*)p)[i]);
}
__device__ inline float sigm(float v){ return 1.f / (1.f + __expf(-v)); }

__device__ inline void gload_lds16(const void* g, void* l){
    __builtin_amdgcn_global_load_lds(
        (const __attribute__((address_space(1))) u32*)g,
        (__attribute__((address_space(3))) u32*)l, 16, 0, 0);
}

struct Ptrs { const void* p[17]; };

// ---------------- k0: dtype detect ----------------
__global__ void k_detect(const void* x, char* ws){
    __shared__ float s[256];
    int tid = threadIdx.x;
    s[tid] = fabsf(bf2f(((const ushort_t*)x)[tid]));
    __syncthreads();
    for (int st = 128; st > 0; st >>= 1){
        if (tid < st) s[tid] = fmaxf(s[tid], s[tid + st]);
        __syncthreads();
    }
    if (tid == 0) *(int*)(ws + O_FLAG) = (s[0] < 1e4f) ? 1 : 0;
}

// ---------------- k1: weight prep ----------------
#define N_PREP 1082792L
__global__ __launch_bounds__(256) void k_prep(Ptrs ps, char* ws){
    const int flag = *(const int*)(ws + O_FLAG);
    long o = (long)blockIdx.x * 256 + threadIdx.x;
    if (o < 384){ ((float*)(ws+O_LNW))[o]  = ldf(ps.p[1],o,flag); return; }  o -= 384;
    if (o < 3072){ ((float*)(ws+O_CONVW))[o]= ldf(ps.p[3],o,flag); return; } o -= 3072;
    if (o < 768){ ((float*)(ws+O_CONVB))[o]= ldf(ps.p[4],o,flag); return; }  o -= 768;
    if (o < 18432){ ((float*)(ws+O_WDT))[o]= ldf(ps.p[6],o,flag); return; }  o -= 18432;
    if (o < 768){ ((float*)(ws+O_DTB))[o]  = ldf(ps.p[7],o,flag); return; }  o -= 768;
    if (o < 768){ ((float*)(ws+O_DSKIP))[o]= ldf(ps.p[9],o,flag); return; }  o -= 768;
    if (o < 294912){ ((float*)(ws+O_WOUT))[o]= ldf(ps.p[10],o,flag); return; } o -= 294912;
    if (o < 98304){ ((float*)(ws+O_WFC))[o]= ldf(ps.p[11],o,flag); return; } o -= 98304;
    if (o < 256){ ((float*)(ws+O_BFC))[o]  = ldf(ps.p[12],o,flag); return; } o -= 256;
    if (o < 256){ ((float*)(ws+O_GAM))[o]  = ldf(ps.p[13],o,flag); return; } o -= 256;
    if (o < 256){ ((float*)(ws+O_BET))[o]  = ldf(ps.p[14],o,flag); return; } o -= 256;
    if (o < 10240){ ((float*)(ws+O_WCLS))[o]= ldf(ps.p[15],o,flag); return; } o -= 10240;
    if (o < 40){ ((float*)(ws+O_BCLS))[o]  = ldf(ps.p[16],o,flag); return; } o -= 40;
    // A = -exp(A_log) * log2(e)   (scan uses exp2)
    if (o < 12288){ ((float*)(ws+O_A))[o]  = -__expf(ldf(ps.p[8],o,flag)) * 1.4426950408889634f; return; } o -= 12288;
    if (o < 589824){                     // W_in [384,1536] -> WinT [1536][384]
        long n = o / 384, k = o % 384;
        ((ushort_t*)(ws+O_WINT))[o] = ldbf(ps.p[2], k*1536 + n, flag); return;
    } o -= 589824;
    if (o < 49152){                      // W_xproj [768,56] -> WxT [64][768], zero-pad n>=56
        long n = o / 768, k = o % 768;
        ((ushort_t*)(ws+O_WXT))[o] = (n < 56) ? ldbf(ps.p[5], k*56 + n, flag) : (ushort_t)0;
        return;
    } o -= 49152;
    if (o < 3072){ ((float*)(ws+O_XMEAN))[o] = 0.f; return; }
}

// ---------------- k2: RMSNorm -> xn (bf16) ----------------
__global__ __launch_bounds__(128) void k_rmsnorm(const void* x, char* ws){
    const int flag = *(const int*)(ws + O_FLAG);
    const float* lnw = (const float*)(ws + O_LNW);
    ushort_t* xn = (ushort_t*)(ws + O_XN);
    long row = blockIdx.x;
    int tid = threadIdx.x;
    float v[3];
    if (flag){
        const ushort_t* xb = (const ushort_t*)x;
        #pragma unroll
        for (int c = 0; c < 3; c++) v[c] = bf2f(xb[row*384 + tid + c*128]);
    } else {
        const float* xf = (const float*)x;
        #pragma unroll
        for (int c = 0; c < 3; c++) v[c] = xf[row*384 + tid + c*128];
    }
    __shared__ float red[128];
    red[tid] = v[0]*v[0] + v[1]*v[1] + v[2]*v[2];
    __syncthreads();
    for (int st = 64; st > 0; st >>= 1){
        if (tid < st) red[tid] += red[tid + st];
        __syncthreads();
    }
    float scale = rsqrtf(red[0] * (1.f/384.f) + 1e-5f);
    #pragma unroll
    for (int c = 0; c < 3; c++)
        xn[row*384 + tid + c*128] = f2bf(v[c] * scale * lnw[tid + c*128]);
}

// ---------------- k3: xmean[b,d] = mean_L x ----------------
__global__ __launch_bounds__(256) void k_xmean(const void* x, char* ws){
    const int flag = *(const int*)(ws + O_FLAG);
    float* xmean = (float*)(ws + O_XMEAN);
    int b = blockIdx.x, d0 = blockIdx.y*128, l0 = blockIdx.z*256;
    int tid = threadIdx.x, dl = tid & 127, lh = tid >> 7;
    float acc = 0.f;
    if (flag){
        const ushort_t* xb = (const ushort_t*)x;
        for (int l = l0 + lh; l < l0 + 256; l += 2)
            acc += bf2f(xb[((long)b*L_ + l)*384 + d0 + dl]);
    } else {
        const float* xf = (const float*)x;
        for (int l = l0 + lh; l < l0 + 256; l += 2)
            acc += xf[((long)b*L_ + l)*384 + d0 + dl];
    }
    __shared__ float s[256];
    s[tid] = acc; __syncthreads();
    if (tid < 128)
        atomicAdd(&xmean[b*384 + d0 + dl], (s[tid] + s[tid+128]) * (1.f/L_));
}

// ---------------- k4: GEMM1  xn @ W_in -> xp | silu(z) ---------
__global__ __launch_bounds__(256) void k_gemm1(char* ws){
    const ushort_t* xn = (const ushort_t*)(ws + O_XN);
    const ushort_t* wT = (const ushort_t*)(ws + O_WINT);
    ushort_t* xp = (ushort_t*)(ws + O_XP);
    ushort_t* zz = (ushort_t*)(ws + O_Z);
    __shared__ ushort_t sA[128*32];
    __shared__ ushort_t sB[128*32];
    int tid = threadIdx.x, w = tid >> 6, l = tid & 63;
    long m0 = (long)blockIdx.x * 128;
    int n0 = blockIdx.y * 128;
    f32x4 acc[4][4] = {};
    int lr = l >> 2, lk = (l & 3) * 8;
    const ushort_t* gA = xn + (m0 + w*16 + lr)*384 + lk;
    const ushort_t* gB = wT + ((long)(n0 + w*16 + lr))*384 + lk;
    ushort_t* lA = &sA[w*16*32];
    ushort_t* lB = &sB[w*16*32];
    int wm = w & 1, wn = w >> 1;
    int arow = wm*64 + (l & 15);
    int brow = wn*64 + (l & 15);
    int koff = (l >> 4) * 8;
    for (int kc = 0; kc < 12; kc++){
        int k0 = kc * 32;
        gload_lds16(gA + k0,           lA);
        gload_lds16(gA + k0 + 64*384,  lA + 64*32);
        gload_lds16(gB + k0,           lB);
        gload_lds16(gB + k0 + 64*384,  lB + 64*32);
        __syncthreads();
        bf16x8 af[4], bfv[4];
        #pragma unroll
        for (int i = 0; i < 4; i++){
            af[i]  = *(const bf16x8*)&sA[(arow + i*16)*32 + koff];
            bfv[i] = *(const bf16x8*)&sB[(brow + i*16)*32 + koff];
        }
        #pragma unroll
        for (int mb = 0; mb < 4; mb++)
            #pragma unroll
            for (int nb = 0; nb < 4; nb++)
                acc[mb][nb] = __builtin_amdgcn_mfma_f32_16x16x32_bf16(af[mb], bfv[nb], acc[mb][nb], 0, 0, 0);
        __syncthreads();
    }
    ushort_t* outp; int nc0; bool isz;
    if (n0 < 768){ outp = xp; nc0 = n0; isz = false; }
    else { outp = zz; nc0 = n0 - 768; isz = true; }
    int rbase = (l >> 4) * 4, cl = l & 15;
    #pragma unroll
    for (int mb = 0; mb < 4; mb++)
        #pragma unroll
        for (int nb = 0; nb < 4; nb++){
            long row = m0 + wm*64 + mb*16 + rbase;
            int col = nc0 + wn*64 + nb*16 + cl;
            #pragma unroll
            for (int r = 0; r < 4; r++){
                float v = acc[mb][nb][r];
                if (isz) v = v * sigm(v);        // fused silu for z
                outp[(row + r)*768 + col] = f2bf(v);
            }
        }
}

// ---------------- k5: causal depthwise conv K=4 + SiLU ----------------
__global__ __launch_bounds__(256) void k_conv(char* ws){
    const ushort_t* xp = (const ushort_t*)(ws + O_XP);
    ushort_t* xc = (ushort_t*)(ws + O_XC);
    const float* cw = (const float*)(ws + O_CONVW);
    const float* cb = (const float*)(ws + O_CONVB);
    int d = blockIdx.x*256 + threadIdx.x;
    int t0 = blockIdx.y * 8;
    int b = blockIdx.z;
    long rbase = (long)b * L_;
    float w0 = cw[d*4], w1 = cw[d*4+1], w2 = cw[d*4+2], w3 = cw[d*4+3];
    float bias = cb[d];
    float xv[11];
    #pragma unroll
    for (int i = 0; i < 11; i++){
        int t = t0 - 3 + i;
        xv[i] = (t >= 0) ? bf2f(xp[(rbase + t)*768 + d]) : 0.f;
    }
    #pragma unroll
    for (int tt = 0; tt < 8; tt++){
        float v = bias + xv[tt]*w0 + xv[tt+1]*w1 + xv[tt+2]*w2 + xv[tt+3]*w3;
        v = v * sigm(v);
        xc[(rbase + t0 + tt)*768 + d] = f2bf(v);
    }
}

// ---------------- k6: xproj  xc @ W_xproj -> x_dbl[32768,56] ----
__global__ __launch_bounds__(256) void k_xproj(char* ws){
    const ushort_t* xc = (const ushort_t*)(ws + O_XC);
    const ushort_t* wT = (const ushort_t*)(ws + O_WXT);
    float* xdbl = (float*)(ws + O_XDBL);
    __shared__ ushort_t sA[128*32];
    __shared__ ushort_t sB[64*32];
    int tid = threadIdx.x, w = tid >> 6, l = tid & 63;
    long m0 = (long)blockIdx.x * 128;
    f32x4 acc[2][4] = {};
    int lr = l >> 2, lk = (l & 3) * 8;
    const ushort_t* gA = xc + (m0 + w*16 + lr)*768 + lk;
    const ushort_t* gB = wT + ((long)(w*16 + lr))*768 + lk;
    ushort_t* lA = &sA[w*16*32];
    ushort_t* lB = &sB[w*16*32];
    int arow0 = w*32 + (l & 15);
    int brow = l & 15;
    int koff = (l >> 4) * 8;
    for (int kc = 0; kc < 24; kc++){
        int k0 = kc * 32;
        gload_lds16(gA + k0,           lA);
        gload_lds16(gA + k0 + 64*768,  lA + 64*32);
        gload_lds16(gB + k0,           lB);
        __syncthreads();
        bf16x8 af[2], bfv[4];
        af[0] = *(const bf16x8*)&sA[arow0*32 + koff];
        af[1] = *(const bf16x8*)&sA[(arow0+16)*32 + koff];
        #pragma unroll
        for (int nb = 0; nb < 4; nb++)
            bfv[nb] = *(const bf16x8*)&sB[(nb*16 + brow)*32 + koff];
        #pragma unroll
        for (int mb = 0; mb < 2; mb++)
            #pragma unroll
            for (int nb = 0; nb < 4; nb++)
                acc[mb][nb] = __builtin_amdgcn_mfma_f32_16x16x32_bf16(af[mb], bfv[nb], acc[mb][nb], 0, 0, 0);
        __syncthreads();
    }
    int rbase = (l >> 4) * 4, cl = l & 15;
    #pragma unroll
    for (int mb = 0; mb < 2; mb++)
        #pragma unroll
        for (int nb = 0; nb < 4; nb++){
            int col = nb*16 + cl;
            if (col < 56){
                long row = m0 + w*32 + mb*16 + rbase;
                #pragma unroll
                for (int r = 0; r < 4; r++)
                    xdbl[(row + r)*56 + col] = acc[mb][nb][r];
            }
        }
}

// ---------------- k7: chunk-parallel selective scan (pass 1) --------------
// R5 post-mortem: global per-step loads exposed ~200cyc latency (VALUBusy
// 48%, dur unchanged). v3 = R5's pk math + one-shot LDS staging of the
// chunk's xdbl (single barrier, zero per-step addr VALU, ds_reads pipeline
// via lgkmcnt) + register double-buffered xc/z group prefetch.
__global__ __launch_bounds__(256, 4) void k_scan(char* ws){
    const ushort_t* xc = (const ushort_t*)(ws + O_XC);
    const ushort_t* wz = (const ushort_t*)(ws + O_Z);      // silu(z)
    const float* xdbl = (const float*)(ws + O_XDBL);
    const float* Ag = (const float*)(ws + O_A);            // -exp(A_log)*log2e
    const float* Dsk = (const float*)(ws + O_DSKIP);
    const float* Wdt = (const float*)(ws + O_WDT);
    const float* dtb = (const float*)(ws + O_DTB);
    float* FX = (float*)(ws + O_FX);
    int tid = threadIdx.x;
    int half = tid & 1, p = tid >> 1;          // 128 d per block, pair = lanes 2k,2k+1
    int d = blockIdx.x * 128 + p;
    int c = blockIdx.y, b = blockIdx.z;
    long row0 = (long)b * L_ + (long)c * CL;

    __shared__ float sXD[CL*56];               // 28 KB: whole chunk's xdbl
    {
        const f32x4* src = (const f32x4*)(xdbl + row0*56);   // 1792 vec4
        f32x4* dst = (f32x4*)sXD;
        #pragma unroll
        for (int i = 0; i < 7; i++) dst[tid + i*256] = src[tid + i*256];
    }

    f32x2 wdt2[6];
    #pragma unroll
    for (int k = 0; k < 6; k++){
        wdt2[k][0] = Wdt[(half*12 + 2*k    )*768 + d];
        wdt2[k][1] = Wdt[(half*12 + 2*k + 1)*768 + d];
    }
    float dbias = half ? 0.f : dtb[d];
    f32x2 Av2[4];
    #pragma unroll
    for (int j = 0; j < 4; j++){
        Av2[j][0] = Ag[d*16 + half*8 + 2*j];
        Av2[j][1] = Ag[d*16 + half*8 + 2*j + 1];
    }
    float Dv = Dsk[d];
    __syncthreads();                           // the only barrier

    f32x2 h2[4], q2[4], G2[4];
    #pragma unroll
    for (int j = 0; j < 4; j++){
        h2[j] = f32x2{0.f, 0.f}; G2[j] = f32x2{0.f, 0.f}; q2[j] = f32x2{1.f, 1.f};
    }
    f32x2 ysum2 = {0.f, 0.f};
    float sdw = 0.f;

    const ushort_t* xcp = xc + row0*768 + d;
    const ushort_t* wzp = wz + row0*768 + d;
    ushort_t curx[8], curz[8], nxtx[8], nxtz[8];
    #pragma unroll
    for (int i = 0; i < 8; i++){ curx[i] = xcp[i*768]; curz[i] = wzp[i*768]; }

    for (int g = 0; g < CL/8; g++){
        if (g + 1 < CL/8){
            #pragma unroll
            for (int i = 0; i < 8; i++){
                nxtx[i] = xcp[(g*8 + 8 + i)*768];
                nxtz[i] = wzp[(g*8 + 8 + i)*768];
            }
        }
        #pragma unroll
        for (int i = 0; i < 8; i++){
            int t = g*8 + i;
            const float* xd = &sXD[t*56];
            // dt partial over this half's 12 dt_r cols (6 pk_fma)
            f32x2 acc2 = {dbias, 0.f};
            #pragma unroll
            for (int j = 0; j < 3; j++){
                f32x4 v = *(const f32x4*)&xd[half*12 + j*4];
                acc2 += f32x2{v[0], v[1]} * wdt2[2*j];
                acc2 += f32x2{v[2], v[3]} * wdt2[2*j + 1];
            }
            float dt_p = acc2[0] + acc2[1];
            float dtv = dt_p + __shfl_xor(dt_p, 1);
            // softplus: ln(1+e^x) = ln2 * log2(1 + 2^(x*log2e))
            float e = __builtin_amdgcn_exp2f(dtv * 1.4426950408889634f);
            float sp = 0.69314718055994531f * __builtin_amdgcn_logf(1.f + e);
            dtv = (dtv > 20.f) ? dtv : sp;

            float xcv = bf2f(curx[i]);
            float wzv = bf2f(curz[i]);
            float u = dtv * xcv;
            f32x2 u2 = {u, u}, wz2 = {wzv, wzv}, dtv2 = {dtv, dtv};
            f32x4 Bva = *(const f32x4*)&xd[24 + half*8];
            f32x4 Bvb = *(const f32x4*)&xd[28 + half*8];
            f32x4 Cva = *(const f32x4*)&xd[40 + half*8];
            f32x4 Cvb = *(const f32x4*)&xd[44 + half*8];
            #pragma unroll
            for (int j = 0; j < 4; j++){
                f32x2 Bj = (j < 2) ? f32x2{Bva[2*j], Bva[2*j+1]} : f32x2{Bvb[2*j-4], Bvb[2*j-3]};
                f32x2 Cj = (j < 2) ? f32x2{Cva[2*j], Cva[2*j+1]} : f32x2{Cvb[2*j-4], Cvb[2*j-3]};
                f32x2 arg = dtv2 * Av2[j];
                f32x2 dA;
                dA[0] = __builtin_amdgcn_exp2f(arg[0]);
                dA[1] = __builtin_amdgcn_exp2f(arg[1]);
                h2[j] = dA * h2[j] + u2 * Bj;
                f32x2 Cw = Cj * wz2;
                ysum2 += h2[j] * Cw;
                q2[j] = q2[j] * dA;
                G2[j] += q2[j] * Cw;
            }
            sdw += xcv * wzv;
        }
        #pragma unroll
        for (int i = 0; i < 8; i++){ curx[i] = nxtx[i]; curz[i] = nxtz[i]; }
    }
    float ys = ysum2[0] + ysum2[1] + (half ? 0.f : Dv * sdw);
    ys += __shfl_xor(ys, 1);
    long fb = ((long)(b*NCHUNK + c)*49)*768 + d;
    if (!half) FX[fb] = ys;
    #pragma unroll
    for (int j = 0; j < 4; j++){
        int sg = half*8 + 2*j;
        FX[fb + (1+sg)*768]  = h2[j][0];  FX[fb + (2+sg)*768]  = h2[j][1];
        FX[fb + (17+sg)*768] = q2[j][0];  FX[fb + (18+sg)*768] = q2[j][1];
        FX[fb + (33+sg)*768] = G2[j][0];  FX[fb + (34+sg)*768] = G2[j][1];
    }
}

// ---------------- k8: scan pass 2 — stitch chunks (thread per (b,d,s)) ----
__global__ __launch_bounds__(256) void k_fix(char* ws){
    const float* FX = (const float*)(ws + O_FX);
    float* ymean = (float*)(ws + O_YMEAN);
    int tid = threadIdx.x;
    int dl = tid & 15, s = tid >> 4;
    int d = blockIdx.x * 16 + dl;
    int b = blockIdx.y;
    float Hrun = 0.f, ys = 0.f;
    for (int c = 0; c < NCHUNK; c++){
        long fb = ((long)(b*NCHUNK + c)*49)*768 + d;
        float Gs = FX[fb + (33+s)*768];
        float Hs = FX[fb + (1+s)*768];
        float qs = FX[fb + (17+s)*768];
        ys += Hrun * Gs;
        if (s == 0) ys += FX[fb];
        Hrun = Hs + qs * Hrun;
    }
    __shared__ float sR[256];
    sR[tid] = ys;
    __syncthreads();
    #pragma unroll
    for (int st = 8; st >= 1; st >>= 1){
        if (s < st) sR[tid] += sR[tid + st*16];
        __syncthreads();
    }
    if (s == 0) ymean[b*768 + d] = sR[dl] * (1.f/L_);
}

// ---------------- k9: head part 1: pooled -> h = pooled@W_fc + b_fc ------
__global__ __launch_bounds__(256) void k_head1(char* ws){
    const float* ymean = (const float*)(ws + O_YMEAN);
    const float* xmean = (const float*)(ws + O_XMEAN);
    const float* Wout = (const float*)(ws + O_WOUT);
    const float* Wfc = (const float*)(ws + O_WFC);
    const float* bfc = (const float*)(ws + O_BFC);
    float* hbuf = (float*)(ws + O_H);
    int b = blockIdx.x, tid = threadIdx.x;
    __shared__ float sY[768];
    __shared__ float sP[384];
    sY[tid] = ymean[b*768 + tid];
    sY[tid+256] = ymean[b*768 + tid + 256];
    sY[tid+512] = ymean[b*768 + tid + 512];
    __syncthreads();
    for (int d = tid; d < 384; d += 256){
        float v = xmean[b*384 + d];
        for (int i = 0; i < 768; i++) v += sY[i] * Wout[i*384 + d];
        sP[d] = v;
    }
    __syncthreads();
    float v = bfc[tid];
    for (int dd = 0; dd < 384; dd++) v += sP[dd] * Wfc[dd*256 + tid];
    hbuf[b*256 + tid] = v;
}

// ---------------- k10: head part 2: batchnorm + relu + classifier --------
__global__ __launch_bounds__(384) void k_head2(char* ws, void* out){
    const int flag = *(const int*)(ws + O_FLAG);
    const float* hbuf = (const float*)(ws + O_H);
    const float* gam = (const float*)(ws + O_GAM);
    const float* bet = (const float*)(ws + O_BET);
    const float* Wcls = (const float*)(ws + O_WCLS);
    const float* bcls = (const float*)(ws + O_BCLS);
    int tid = threadIdx.x;
    __shared__ float sH[8*256];
    if (tid < 256){
        float hv[8]; float mu = 0.f;
        #pragma unroll
        for (int b = 0; b < 8; b++){ hv[b] = hbuf[b*256 + tid]; mu += hv[b]; }
        mu *= 0.125f;
        float var = 0.f;
        #pragma unroll
        for (int b = 0; b < 8; b++){ float dv = hv[b]-mu; var += dv*dv; }
        var *= 0.125f;
        float rs = rsqrtf(var + 1e-5f);
        #pragma unroll
        for (int b = 0; b < 8; b++){
            float t = (hv[b]-mu)*rs*gam[tid] + bet[tid];
            sH[b*256 + tid] = t > 0.f ? t : 0.f;
        }
    }
    __syncthreads();
    if (tid < 320){
        int b = tid / 40, c = tid % 40;
        float acc = bcls[c];
        for (int j = 0; j < 256; j++) acc += sH[b*256 + j] * Wcls[j*40 + c];
        if (flag) ((ushort_t*)out)[b*40 + c] = f2bf(acc);
        else      ((float*)out)[b*40 + c] = acc;
    }
}

// ---------------- launch ----------------
extern "C" void kernel_launch(void* const* d_in, const int* in_sizes, int n_in,
                              void* d_out, int out_size, void* d_ws, size_t ws_size,
                              hipStream_t stream){
    (void)in_sizes; (void)n_in; (void)out_size; (void)ws_size;
    char* ws = (char*)d_ws;
    Ptrs ps;
    for (int i = 0; i < 17; i++) ps.p[i] = d_in[i];

    k_detect<<<1, 256, 0, stream>>>(d_in[0], ws);
    k_prep<<<(unsigned)((N_PREP + 255) / 256), 256, 0, stream>>>(ps, ws);
    k_rmsnorm<<<ML_, 128, 0, stream>>>(d_in[0], ws);
    k_xmean<<<dim3(8, 3, 16), 256, 0, stream>>>(d_in[0], ws);
    k_gemm1<<<dim3(ML_/128, 12), 256, 0, stream>>>(ws);
    k_conv<<<dim3(3, L_/8, B_), 256, 0, stream>>>(ws);
    k_xproj<<<ML_/128, 256, 0, stream>>>(ws);
    k_scan<<<dim3(6, NCHUNK, B_), 256, 0, stream>>>(ws);
    k_fix<<<dim3(48, B_), 256, 0, stream>>>(ws);
    k_head1<<<B_, 256, 0, stream>>>(ws);
    k_head2<<<1, 384, 0, stream>>>(ws, d_out);
}

// Round 7
// 509.256 us; speedup vs baseline: 7.2857x; 1.0855x over previous
//
#include <hip/hip_runtime.h>

typedef unsigned short ushort_t;
typedef unsigned int u32;
typedef float f32x4 __attribute__((ext_vector_type(4)));
typedef float f32x2 __attribute__((ext_vector_type(2)));
typedef __bf16 bf16x8 __attribute__((ext_vector_type(8)));

#define B_ 8
#define L_ 4096
#define D_ 384
#define DI_ 768
#define S_ 16
#define NC_ 40
#define ML_ (B_*L_)   // 32768 rows
#define NCHUNK 32
#define CL 128        // chunk length (L_/NCHUNK)

// ---------------- workspace layout (bytes) ----------------
// ~154 MB total. Aliasing:
//   XN lives in XC region (dead after gemm1, before conv writes XC);
//   XDBL lives at start of XP region (XP dead after conv);
//   FX (chunk summaries, 38.5 MB) lives in XP region after XDBL.
constexpr size_t au(size_t x){ return (x + 255) & ~size_t(255); }
constexpr size_t O_FLAG = 0;                                   // int
constexpr size_t O_LNW  = 256;                                 // 384 f32
constexpr size_t O_CONVW= au(O_LNW  + 384*4);                  // 3072 f32
constexpr size_t O_CONVB= au(O_CONVW+ 3072*4);                 // 768 f32
constexpr size_t O_WDT  = au(O_CONVB+ 768*4);                  // 18432 f32
constexpr size_t O_DTB  = au(O_WDT  + 18432*4);                // 768 f32
constexpr size_t O_A    = au(O_DTB  + 768*4);                  // 12288 f32 (A = -exp(A_log)*log2e)
constexpr size_t O_DSKIP= au(O_A    + 12288*4);                // 768 f32
constexpr size_t O_WOUT = au(O_DSKIP+ 768*4);                  // 294912 f32
constexpr size_t O_WFC  = au(O_WOUT + 294912*4);               // 98304 f32
constexpr size_t O_BFC  = au(O_WFC  + 98304*4);                // 256 f32
constexpr size_t O_GAM  = au(O_BFC  + 256*4);
constexpr size_t O_BET  = au(O_GAM  + 256*4);
constexpr size_t O_WCLS = au(O_BET  + 256*4);                  // 10240 f32
constexpr size_t O_BCLS = au(O_WCLS + 10240*4);                // 40 f32
constexpr size_t O_XMEAN= au(O_BCLS + 40*4);                   // 8*384 f32 (atomic acc, zeroed in prep)
constexpr size_t O_YMEAN= au(O_XMEAN+ 3072*4);                 // 8*768 f32
constexpr size_t O_H    = au(O_YMEAN+ 6144*4);                 // 8*256 f32
constexpr size_t O_WINT = au(O_H    + 2048*4);                 // W_in^T  [1536][384] bf16
constexpr size_t O_WXT  = au(O_WINT + (size_t)589824*2);       // W_xproj^T padded [64][768] bf16
constexpr size_t O_XP   = au(O_WXT  + (size_t)49152*2);        // [32768][768] bf16
constexpr size_t O_XDBL = O_XP;                                // alias: [32768][56] f32 (after conv)
constexpr size_t O_FX   = au(O_XDBL + (size_t)ML_*56*4);       // [b][c][49][768] f32 chunk summaries
constexpr size_t FX_SZ  = (size_t)B_*NCHUNK*49*768*4;          // 38.5 MB
constexpr size_t O_Z    = au(O_XP   + (size_t)ML_*768*2);      // [32768][768] bf16 (holds silu(z))
constexpr size_t O_XCU  = au(O_Z    + (size_t)ML_*768*2);      // union region, 50.3 MB
constexpr size_t O_XN   = O_XCU;                               // [32768][384] bf16 (dead after gemm1)
constexpr size_t O_XC   = O_XCU;                               // [32768][768] bf16
constexpr size_t WS_NEED= O_XCU + (size_t)ML_*768*2;           // ~154 MB
static_assert(O_FX + FX_SZ <= O_Z, "FX must fit in dead XP tail");

// ---------------- helpers ----------------
__device__ inline float bf2f(ushort_t u){ return __uint_as_float(((u32)u) << 16); }
__device__ inline ushort_t f2bf(float f){
    u32 x = __float_as_uint(f);
    u32 r = (x + 0x7fffu + ((x >> 16) & 1u)) >> 16;   // RNE
    return (ushort_t)r;
}
__device__ inline float ldf(const void* p, long i, int flag){
    return flag ? bf2f(((const ushort_t*)p)[i]) : ((const float*)p)[i];
}
__device__ inline ushort_t ldbf(const void* p, long i, int flag){
    return flag ? ((const ushort_t*)p)[i] : f2bf(((const float*)p)[i]);
}
__device__ inline float sigm(float v){ return 1.f / (1.f + __expf(-v)); }

__device__ inline void gload_lds16(const void* g, void* l){
    __builtin_amdgcn_global_load_lds(
        (const __attribute__((address_space(1))) u32*)g,
        (__attribute__((address_space(3))) u32*)l, 16, 0, 0);
}

struct Ptrs { const void* p[17]; };

// ---------------- k0: dtype detect ----------------
__global__ void k_detect(const void* x, char* ws){
    __shared__ float s[256];
    int tid = threadIdx.x;
    s[tid] = fabsf(bf2f(((const ushort_t*)x)[tid]));
    __syncthreads();
    for (int st = 128; st > 0; st >>= 1){
        if (tid < st) s[tid] = fmaxf(s[tid], s[tid + st]);
        __syncthreads();
    }
    if (tid == 0) *(int*)(ws + O_FLAG) = (s[0] < 1e4f) ? 1 : 0;
}

// ---------------- k1: weight prep ----------------
#define N_PREP 1082792L
__global__ __launch_bounds__(256) void k_prep(Ptrs ps, char* ws){
    const int flag = *(const int*)(ws + O_FLAG);
    long o = (long)blockIdx.x * 256 + threadIdx.x;
    if (o < 384){ ((float*)(ws+O_LNW))[o]  = ldf(ps.p[1],o,flag); return; }  o -= 384;
    if (o < 3072){ ((float*)(ws+O_CONVW))[o]= ldf(ps.p[3],o,flag); return; } o -= 3072;
    if (o < 768){ ((float*)(ws+O_CONVB))[o]= ldf(ps.p[4],o,flag); return; }  o -= 768;
    if (o < 18432){ ((float*)(ws+O_WDT))[o]= ldf(ps.p[6],o,flag); return; }  o -= 18432;
    if (o < 768){ ((float*)(ws+O_DTB))[o]  = ldf(ps.p[7],o,flag); return; }  o -= 768;
    if (o < 768){ ((float*)(ws+O_DSKIP))[o]= ldf(ps.p[9],o,flag); return; }  o -= 768;
    if (o < 294912){ ((float*)(ws+O_WOUT))[o]= ldf(ps.p[10],o,flag); return; } o -= 294912;
    if (o < 98304){ ((float*)(ws+O_WFC))[o]= ldf(ps.p[11],o,flag); return; } o -= 98304;
    if (o < 256){ ((float*)(ws+O_BFC))[o]  = ldf(ps.p[12],o,flag); return; } o -= 256;
    if (o < 256){ ((float*)(ws+O_GAM))[o]  = ldf(ps.p[13],o,flag); return; } o -= 256;
    if (o < 256){ ((float*)(ws+O_BET))[o]  = ldf(ps.p[14],o,flag); return; } o -= 256;
    if (o < 10240){ ((float*)(ws+O_WCLS))[o]= ldf(ps.p[15],o,flag); return; } o -= 10240;
    if (o < 40){ ((float*)(ws+O_BCLS))[o]  = ldf(ps.p[16],o,flag); return; } o -= 40;
    // A = -exp(A_log) * log2(e)   (scan uses exp2)
    if (o < 12288){ ((float*)(ws+O_A))[o]  = -__expf(ldf(ps.p[8],o,flag)) * 1.4426950408889634f; return; } o -= 12288;
    if (o < 589824){                     // W_in [384,1536] -> WinT [1536][384]
        long n = o / 384, k = o % 384;
        ((ushort_t*)(ws+O_WINT))[o] = ldbf(ps.p[2], k*1536 + n, flag); return;
    } o -= 589824;
    if (o < 49152){                      // W_xproj [768,56] -> WxT [64][768], zero-pad n>=56
        long n = o / 768, k = o % 768;
        ((ushort_t*)(ws+O_WXT))[o] = (n < 56) ? ldbf(ps.p[5], k*56 + n, flag) : (ushort_t)0;
        return;
    } o -= 49152;
    if (o < 3072){ ((float*)(ws+O_XMEAN))[o] = 0.f; return; }
}

// ---------------- k2: RMSNorm -> xn (bf16) ----------------
__global__ __launch_bounds__(128) void k_rmsnorm(const void* x, char* ws){
    const int flag = *(const int*)(ws + O_FLAG);
    const float* lnw = (const float*)(ws + O_LNW);
    ushort_t* xn = (ushort_t*)(ws + O_XN);
    long row = blockIdx.x;
    int tid = threadIdx.x;
    float v[3];
    if (flag){
        const ushort_t* xb = (const ushort_t*)x;
        #pragma unroll
        for (int c = 0; c < 3; c++) v[c] = bf2f(xb[row*384 + tid + c*128]);
    } else {
        const float* xf = (const float*)x;
        #pragma unroll
        for (int c = 0; c < 3; c++) v[c] = xf[row*384 + tid + c*128];
    }
    __shared__ float red[128];
    red[tid] = v[0]*v[0] + v[1]*v[1] + v[2]*v[2];
    __syncthreads();
    for (int st = 64; st > 0; st >>= 1){
        if (tid < st) red[tid] += red[tid + st];
        __syncthreads();
    }
    float scale = rsqrtf(red[0] * (1.f/384.f) + 1e-5f);
    #pragma unroll
    for (int c = 0; c < 3; c++)
        xn[row*384 + tid + c*128] = f2bf(v[c] * scale * lnw[tid + c*128]);
}

// ---------------- k3: xmean[b,d] = mean_L x ----------------
__global__ __launch_bounds__(256) void k_xmean(const void* x, char* ws){
    const int flag = *(const int*)(ws + O_FLAG);
    float* xmean = (float*)(ws + O_XMEAN);
    int b = blockIdx.x, d0 = blockIdx.y*128, l0 = blockIdx.z*256;
    int tid = threadIdx.x, dl = tid & 127, lh = tid >> 7;
    float acc = 0.f;
    if (flag){
        const ushort_t* xb = (const ushort_t*)x;
        for (int l = l0 + lh; l < l0 + 256; l += 2)
            acc += bf2f(xb[((long)b*L_ + l)*384 + d0 + dl]);
    } else {
        const float* xf = (const float*)x;
        for (int l = l0 + lh; l < l0 + 256; l += 2)
            acc += xf[((long)b*L_ + l)*384 + d0 + dl];
    }
    __shared__ float s[256];
    s[tid] = acc; __syncthreads();
    if (tid < 128)
        atomicAdd(&xmean[b*384 + d0 + dl], (s[tid] + s[tid+128]) * (1.f/L_));
}

// ---------------- k4: GEMM1  xn @ W_in -> xp | silu(z) ---------
__global__ __launch_bounds__(256) void k_gemm1(char* ws){
    const ushort_t* xn = (const ushort_t*)(ws + O_XN);
    const ushort_t* wT = (const ushort_t*)(ws + O_WINT);
    ushort_t* xp = (ushort_t*)(ws + O_XP);
    ushort_t* zz = (ushort_t*)(ws + O_Z);
    __shared__ ushort_t sA[128*32];
    __shared__ ushort_t sB[128*32];
    int tid = threadIdx.x, w = tid >> 6, l = tid & 63;
    long m0 = (long)blockIdx.x * 128;
    int n0 = blockIdx.y * 128;
    f32x4 acc[4][4] = {};
    int lr = l >> 2, lk = (l & 3) * 8;
    const ushort_t* gA = xn + (m0 + w*16 + lr)*384 + lk;
    const ushort_t* gB = wT + ((long)(n0 + w*16 + lr))*384 + lk;
    ushort_t* lA = &sA[w*16*32];
    ushort_t* lB = &sB[w*16*32];
    int wm = w & 1, wn = w >> 1;
    int arow = wm*64 + (l & 15);
    int brow = wn*64 + (l & 15);
    int koff = (l >> 4) * 8;
    for (int kc = 0; kc < 12; kc++){
        int k0 = kc * 32;
        gload_lds16(gA + k0,           lA);
        gload_lds16(gA + k0 + 64*384,  lA + 64*32);
        gload_lds16(gB + k0,           lB);
        gload_lds16(gB + k0 + 64*384,  lB + 64*32);
        __syncthreads();
        bf16x8 af[4], bfv[4];
        #pragma unroll
        for (int i = 0; i < 4; i++){
            af[i]  = *(const bf16x8*)&sA[(arow + i*16)*32 + koff];
            bfv[i] = *(const bf16x8*)&sB[(brow + i*16)*32 + koff];
        }
        #pragma unroll
        for (int mb = 0; mb < 4; mb++)
            #pragma unroll
            for (int nb = 0; nb < 4; nb++)
                acc[mb][nb] = __builtin_amdgcn_mfma_f32_16x16x32_bf16(af[mb], bfv[nb], acc[mb][nb], 0, 0, 0);
        __syncthreads();
    }
    ushort_t* outp; int nc0; bool isz;
    if (n0 < 768){ outp = xp; nc0 = n0; isz = false; }
    else { outp = zz; nc0 = n0 - 768; isz = true; }
    int rbase = (l >> 4) * 4, cl = l & 15;
    #pragma unroll
    for (int mb = 0; mb < 4; mb++)
        #pragma unroll
        for (int nb = 0; nb < 4; nb++){
            long row = m0 + wm*64 + mb*16 + rbase;
            int col = nc0 + wn*64 + nb*16 + cl;
            #pragma unroll
            for (int r = 0; r < 4; r++){
                float v = acc[mb][nb][r];
                if (isz) v = v * sigm(v);        // fused silu for z
                outp[(row + r)*768 + col] = f2bf(v);
            }
        }
}

// ---------------- k5: causal depthwise conv K=4 + SiLU ----------------
__global__ __launch_bounds__(256) void k_conv(char* ws){
    const ushort_t* xp = (const ushort_t*)(ws + O_XP);
    ushort_t* xc = (ushort_t*)(ws + O_XC);
    const float* cw = (const float*)(ws + O_CONVW);
    const float* cb = (const float*)(ws + O_CONVB);
    int d = blockIdx.x*256 + threadIdx.x;
    int t0 = blockIdx.y * 8;
    int b = blockIdx.z;
    long rbase = (long)b * L_;
    float w0 = cw[d*4], w1 = cw[d*4+1], w2 = cw[d*4+2], w3 = cw[d*4+3];
    float bias = cb[d];
    float xv[11];
    #pragma unroll
    for (int i = 0; i < 11; i++){
        int t = t0 - 3 + i;
        xv[i] = (t >= 0) ? bf2f(xp[(rbase + t)*768 + d]) : 0.f;
    }
    #pragma unroll
    for (int tt = 0; tt < 8; tt++){
        float v = bias + xv[tt]*w0 + xv[tt+1]*w1 + xv[tt+2]*w2 + xv[tt+3]*w3;
        v = v * sigm(v);
        xc[(rbase + t0 + tt)*768 + d] = f2bf(v);
    }
}

// ---------------- k6: xproj  xc @ W_xproj -> x_dbl[32768,56] ----
__global__ __launch_bounds__(256) void k_xproj(char* ws){
    const ushort_t* xc = (const ushort_t*)(ws + O_XC);
    const ushort_t* wT = (const ushort_t*)(ws + O_WXT);
    float* xdbl = (float*)(ws + O_XDBL);
    __shared__ ushort_t sA[128*32];
    __shared__ ushort_t sB[64*32];
    int tid = threadIdx.x, w = tid >> 6, l = tid & 63;
    long m0 = (long)blockIdx.x * 128;
    f32x4 acc[2][4] = {};
    int lr = l >> 2, lk = (l & 3) * 8;
    const ushort_t* gA = xc + (m0 + w*16 + lr)*768 + lk;
    const ushort_t* gB = wT + ((long)(w*16 + lr))*768 + lk;
    ushort_t* lA = &sA[w*16*32];
    ushort_t* lB = &sB[w*16*32];
    int arow0 = w*32 + (l & 15);
    int brow = l & 15;
    int koff = (l >> 4) * 8;
    for (int kc = 0; kc < 24; kc++){
        int k0 = kc * 32;
        gload_lds16(gA + k0,           lA);
        gload_lds16(gA + k0 + 64*768,  lA + 64*32);
        gload_lds16(gB + k0,           lB);
        __syncthreads();
        bf16x8 af[2], bfv[4];
        af[0] = *(const bf16x8*)&sA[arow0*32 + koff];
        af[1] = *(const bf16x8*)&sA[(arow0+16)*32 + koff];
        #pragma unroll
        for (int nb = 0; nb < 4; nb++)
            bfv[nb] = *(const bf16x8*)&sB[(nb*16 + brow)*32 + koff];
        #pragma unroll
        for (int mb = 0; mb < 2; mb++)
            #pragma unroll
            for (int nb = 0; nb < 4; nb++)
                acc[mb][nb] = __builtin_amdgcn_mfma_f32_16x16x32_bf16(af[mb], bfv[nb], acc[mb][nb], 0, 0, 0);
        __syncthreads();
    }
    int rbase = (l >> 4) * 4, cl = l & 15;
    #pragma unroll
    for (int mb = 0; mb < 2; mb++)
        #pragma unroll
        for (int nb = 0; nb < 4; nb++){
            int col = nb*16 + cl;
            if (col < 56){
                long row = m0 + w*32 + mb*16 + rbase;
                #pragma unroll
                for (int r = 0; r < 4; r++)
                    xdbl[(row + r)*56 + col] = acc[mb][nb][r];
            }
        }
}

// ---------------- k7: chunk-parallel selective scan (pass 1) --------------
// v4. R6 post-mortem: manual 8-deep register prefetch of xc/z spilled
// (~140 MB scratch traffic, VGPR report 64 + scratch). v4 keeps the one-shot
// LDS staging of xdbl (single barrier, R6's win) and replaces the prefetch
// with R5's parity-split per-step load: half 0 loads xc, half 1 loads
// silu(z), exchanged via shfl_xor(1) (DPP). launch_bounds(256,5): 102-VGPR
// cap -> LDS (28KB) limits occupancy at 5 blocks/CU (20 waves).
__global__ __launch_bounds__(256, 5) void k_scan(char* ws){
    const ushort_t* xc = (const ushort_t*)(ws + O_XC);
    const ushort_t* wz = (const ushort_t*)(ws + O_Z);      // silu(z)
    const float* xdbl = (const float*)(ws + O_XDBL);
    const float* Ag = (const float*)(ws + O_A);            // -exp(A_log)*log2e
    const float* Dsk = (const float*)(ws + O_DSKIP);
    const float* Wdt = (const float*)(ws + O_WDT);
    const float* dtb = (const float*)(ws + O_DTB);
    float* FX = (float*)(ws + O_FX);
    int tid = threadIdx.x;
    int half = tid & 1, p = tid >> 1;          // 128 d per block, pair = lanes 2k,2k+1
    int d = blockIdx.x * 128 + p;
    int c = blockIdx.y, b = blockIdx.z;
    long row0 = (long)b * L_ + (long)c * CL;

    __shared__ float sXD[CL*56];               // 28 KB: whole chunk's xdbl
    {
        const f32x4* src = (const f32x4*)(xdbl + row0*56);   // 1792 vec4
        f32x4* dst = (f32x4*)sXD;
        #pragma unroll
        for (int i = 0; i < 7; i++) dst[tid + i*256] = src[tid + i*256];
    }

    f32x2 wdt2[6];
    #pragma unroll
    for (int k = 0; k < 6; k++){
        wdt2[k][0] = Wdt[(half*12 + 2*k    )*768 + d];
        wdt2[k][1] = Wdt[(half*12 + 2*k + 1)*768 + d];
    }
    float dbias = half ? 0.f : dtb[d];
    f32x2 Av2[4];
    #pragma unroll
    for (int j = 0; j < 4; j++){
        Av2[j][0] = Ag[d*16 + half*8 + 2*j];
        Av2[j][1] = Ag[d*16 + half*8 + 2*j + 1];
    }
    float Dv = Dsk[d];
    __syncthreads();                           // the only barrier

    f32x2 h2[4], q2[4], G2[4];
    #pragma unroll
    for (int j = 0; j < 4; j++){
        h2[j] = f32x2{0.f, 0.f}; G2[j] = f32x2{0.f, 0.f}; q2[j] = f32x2{1.f, 1.f};
    }
    f32x2 ysum2 = {0.f, 0.f};
    float sdw = 0.f;

    const ushort_t* gx = (half ? wz : xc) + row0*768 + d;   // parity-split stream
    #pragma unroll 8
    for (int t = 0; t < CL; t++){
        ushort_t mine = gx[t*768];
        const float* xd = &sXD[t*56];
        // dt partial over this half's 12 dt_r cols (6 pk_fma)
        f32x2 acc2 = {dbias, 0.f};
        #pragma unroll
        for (int j = 0; j < 3; j++){
            f32x4 v = *(const f32x4*)&xd[half*12 + j*4];
            acc2 += f32x2{v[0], v[1]} * wdt2[2*j];
            acc2 += f32x2{v[2], v[3]} * wdt2[2*j + 1];
        }
        float dt_p = acc2[0] + acc2[1];
        float dtv = dt_p + __shfl_xor(dt_p, 1);
        // softplus: ln(1+e^x) = ln2 * log2(1 + 2^(x*log2e))
        float e = __builtin_amdgcn_exp2f(dtv * 1.4426950408889634f);
        float sp = 0.69314718055994531f * __builtin_amdgcn_logf(1.f + e);
        dtv = (dtv > 20.f) ? dtv : sp;

        u32 other = (u32)__shfl_xor((int)(u32)mine, 1);
        float xcv = bf2f(half ? (ushort_t)other : mine);
        float wzv = bf2f(half ? mine : (ushort_t)other);
        float u = dtv * xcv;
        f32x2 u2 = {u, u}, wz2 = {wzv, wzv}, dtv2 = {dtv, dtv};
        f32x4 Bva = *(const f32x4*)&xd[24 + half*8];
        f32x4 Bvb = *(const f32x4*)&xd[28 + half*8];
        f32x4 Cva = *(const f32x4*)&xd[40 + half*8];
        f32x4 Cvb = *(const f32x4*)&xd[44 + half*8];
        #pragma unroll
        for (int j = 0; j < 4; j++){
            f32x2 Bj = (j < 2) ? f32x2{Bva[2*j], Bva[2*j+1]} : f32x2{Bvb[2*j-4], Bvb[2*j-3]};
            f32x2 Cj = (j < 2) ? f32x2{Cva[2*j], Cva[2*j+1]} : f32x2{Cvb[2*j-4], Cvb[2*j-3]};
            f32x2 arg = dtv2 * Av2[j];
            f32x2 dA;
            dA[0] = __builtin_amdgcn_exp2f(arg[0]);
            dA[1] = __builtin_amdgcn_exp2f(arg[1]);
            h2[j] = dA * h2[j] + u2 * Bj;
            f32x2 Cw = Cj * wz2;
            ysum2 += h2[j] * Cw;
            q2[j] = q2[j] * dA;
            G2[j] += q2[j] * Cw;
        }
        sdw += xcv * wzv;
    }
    float ys = ysum2[0] + ysum2[1] + (half ? 0.f : Dv * sdw);
    ys += __shfl_xor(ys, 1);
    long fb = ((long)(b*NCHUNK + c)*49)*768 + d;
    if (!half) FX[fb] = ys;
    #pragma unroll
    for (int j = 0; j < 4; j++){
        int sg = half*8 + 2*j;
        FX[fb + (1+sg)*768]  = h2[j][0];  FX[fb + (2+sg)*768]  = h2[j][1];
        FX[fb + (17+sg)*768] = q2[j][0];  FX[fb + (18+sg)*768] = q2[j][1];
        FX[fb + (33+sg)*768] = G2[j][0];  FX[fb + (34+sg)*768] = G2[j][1];
    }
}

// ---------------- k8: scan pass 2 — stitch chunks (thread per (b,d,s)) ----
__global__ __launch_bounds__(256) void k_fix(char* ws){
    const float* FX = (const float*)(ws + O_FX);
    float* ymean = (float*)(ws + O_YMEAN);
    int tid = threadIdx.x;
    int dl = tid & 15, s = tid >> 4;
    int d = blockIdx.x * 16 + dl;
    int b = blockIdx.y;
    float Hrun = 0.f, ys = 0.f;
    for (int c = 0; c < NCHUNK; c++){
        long fb = ((long)(b*NCHUNK + c)*49)*768 + d;
        float Gs = FX[fb + (33+s)*768];
        float Hs = FX[fb + (1+s)*768];
        float qs = FX[fb + (17+s)*768];
        ys += Hrun * Gs;
        if (s == 0) ys += FX[fb];
        Hrun = Hs + qs * Hrun;
    }
    __shared__ float sR[256];
    sR[tid] = ys;
    __syncthreads();
    #pragma unroll
    for (int st = 8; st >= 1; st >>= 1){
        if (s < st) sR[tid] += sR[tid + st*16];
        __syncthreads();
    }
    if (s == 0) ymean[b*768 + d] = sR[dl] * (1.f/L_);
}

// ---------------- k9: head part 1: pooled -> h = pooled@W_fc + b_fc ------
__global__ __launch_bounds__(256) void k_head1(char* ws){
    const float* ymean = (const float*)(ws + O_YMEAN);
    const float* xmean = (const float*)(ws + O_XMEAN);
    const float* Wout = (const float*)(ws + O_WOUT);
    const float* Wfc = (const float*)(ws + O_WFC);
    const float* bfc = (const float*)(ws + O_BFC);
    float* hbuf = (float*)(ws + O_H);
    int b = blockIdx.x, tid = threadIdx.x;
    __shared__ float sY[768];
    __shared__ float sP[384];
    sY[tid] = ymean[b*768 + tid];
    sY[tid+256] = ymean[b*768 + tid + 256];
    sY[tid+512] = ymean[b*768 + tid + 512];
    __syncthreads();
    for (int d = tid; d < 384; d += 256){
        float v = xmean[b*384 + d];
        for (int i = 0; i < 768; i++) v += sY[i] * Wout[i*384 + d];
        sP[d] = v;
    }
    __syncthreads();
    float v = bfc[tid];
    for (int dd = 0; dd < 384; dd++) v += sP[dd] * Wfc[dd*256 + tid];
    hbuf[b*256 + tid] = v;
}

// ---------------- k10: head part 2: batchnorm + relu + classifier --------
__global__ __launch_bounds__(384) void k_head2(char* ws, void* out){
    const int flag = *(const int*)(ws + O_FLAG);
    const float* hbuf = (const float*)(ws + O_H);
    const float* gam = (const float*)(ws + O_GAM);
    const float* bet = (const float*)(ws + O_BET);
    const float* Wcls = (const float*)(ws + O_WCLS);
    const float* bcls = (const float*)(ws + O_BCLS);
    int tid = threadIdx.x;
    __shared__ float sH[8*256];
    if (tid < 256){
        float hv[8]; float mu = 0.f;
        #pragma unroll
        for (int b = 0; b < 8; b++){ hv[b] = hbuf[b*256 + tid]; mu += hv[b]; }
        mu *= 0.125f;
        float var = 0.f;
        #pragma unroll
        for (int b = 0; b < 8; b++){ float dv = hv[b]-mu; var += dv*dv; }
        var *= 0.125f;
        float rs = rsqrtf(var + 1e-5f);
        #pragma unroll
        for (int b = 0; b < 8; b++){
            float t = (hv[b]-mu)*rs*gam[tid] + bet[tid];
            sH[b*256 + tid] = t > 0.f ? t : 0.f;
        }
    }
    __syncthreads();
    if (tid < 320){
        int b = tid / 40, c = tid % 40;
        float acc = bcls[c];
        for (int j = 0; j < 256; j++) acc += sH[b*256 + j] * Wcls[j*40 + c];
        if (flag) ((ushort_t*)out)[b*40 + c] = f2bf(acc);
        else      ((float*)out)[b*40 + c] = acc;
    }
}

// ---------------- launch ----------------
extern "C" void kernel_launch(void* const* d_in, const int* in_sizes, int n_in,
                              void* d_out, int out_size, void* d_ws, size_t ws_size,
                              hipStream_t stream){
    (void)in_sizes; (void)n_in; (void)out_size; (void)ws_size;
    char* ws = (char*)d_ws;
    Ptrs ps;
    for (int i = 0; i < 17; i++) ps.p[i] = d_in[i];

    k_detect<<<1, 256, 0, stream>>>(d_in[0], ws);
    k_prep<<<(unsigned)((N_PREP + 255) / 256), 256, 0, stream>>>(ps, ws);
    k_rmsnorm<<<ML_, 128, 0, stream>>>(d_in[0], ws);
    k_xmean<<<dim3(8, 3, 16), 256, 0, stream>>>(d_in[0], ws);
    k_gemm1<<<dim3(ML_/128, 12), 256, 0, stream>>>(ws);
    k_conv<<<dim3(3, L_/8, B_), 256, 0, stream>>>(ws);
    k_xproj<<<ML_/128, 256, 0, stream>>>(ws);
    k_scan<<<dim3(6, NCHUNK, B_), 256, 0, stream>>>(ws);
    k_fix<<<dim3(48, B_), 256, 0, stream>>>(ws);
    k_head1<<<B_, 256, 0, stream>>>(ws);
    k_head2<<<1, 384, 0, stream>>>(ws, d_out);
}